// Round 4
// baseline (1527.567 us; speedup 1.0000x reference)
//
#include <hip/hip_runtime.h>
#include <hip/hip_bf16.h>
#include <math.h>

#define NEG_SLOPE 0.2f
#define SM_EPS 1e-16f

// ---------------------------------------------------------------------------
// CSR build: count degrees, exclusive-scan, scatter src ids grouped by dst.
// Edges are identical for layer 1 and layer 2, so we build CSR once per call.
// ---------------------------------------------------------------------------

__global__ void count_deg(const int* __restrict__ edge, int* __restrict__ deg, int E) {
    int t = blockIdx.x * blockDim.x + threadIdx.x;
    if (t < E) {
        int dst = edge[E + t];
        atomicAdd(&deg[dst], 1);
    }
}

// One block (1024 threads) per relation: sequential chunked scan over N values.
__global__ void scan_deg(const int* __restrict__ deg3, int* __restrict__ rp3,
                         int* __restrict__ cur3, int N) {
    int r = blockIdx.x;
    const int* deg = deg3 + (size_t)r * N;
    int* rp  = rp3 + (size_t)r * (N + 1);
    int* cur = cur3 + (size_t)r * N;
    __shared__ int wsum[16];
    __shared__ int total_s;
    int tid = threadIdx.x, lane = tid & 63, wid = tid >> 6;
    int carry = 0;
    for (int base = 0; base < N; base += 1024) {
        int i = base + tid;
        int v = (i < N) ? deg[i] : 0;
        int incl = v;
        #pragma unroll
        for (int off = 1; off < 64; off <<= 1) {
            int t2 = __shfl_up(incl, off);
            if (lane >= off) incl += t2;
        }
        if (lane == 63) wsum[wid] = incl;
        __syncthreads();
        if (wid == 0 && lane < 16) {
            int w = wsum[lane];
            int winc = w;
            #pragma unroll
            for (int off = 1; off < 16; off <<= 1) {
                int t2 = __shfl_up(winc, off);
                if (lane >= off) winc += t2;
            }
            wsum[lane] = winc - w;  // exclusive
            if (lane == 15) total_s = winc;
        }
        __syncthreads();
        int excl = carry + wsum[wid] + (incl - v);
        if (i < N) { rp[i] = excl; cur[i] = excl; }
        carry += total_s;
        __syncthreads();
    }
    if (tid == 0) rp[N] = carry;
}

__global__ void scatter_edges(const int* __restrict__ edge, int* __restrict__ cur,
                              int* __restrict__ csrc, int E) {
    int t = blockIdx.x * blockDim.x + threadIdx.x;
    if (t < E) {
        int src = edge[t];
        int dst = edge[E + t];
        int pos = atomicAdd(&cur[dst], 1);
        csrc[pos] = src;
    }
}

// ---------------------------------------------------------------------------
// Dual fp32 GEMM: C0 = A @ B0, C1 = A @ B1  (M x 128 @ 128 x 128).
// blockIdx.y selects (B0,C0) or (B1,C1). 128x128 tile per block, 8x8 per
// thread, K chunked by 8 through LDS (A stored k-major for broadcast reads).
// ---------------------------------------------------------------------------

__global__ __launch_bounds__(256) void gemm2(const float* __restrict__ A,
                                             const float* __restrict__ B0,
                                             const float* __restrict__ B1,
                                             float* __restrict__ C0,
                                             float* __restrict__ C1, int M) {
    const float* B = blockIdx.y ? B1 : B0;
    float* C = blockIdx.y ? C1 : C0;
    __shared__ float As[8][128];
    __shared__ float Bs[8][128];
    int tid = threadIdx.x;
    int bm = blockIdx.x * 128;
    int lrow = tid >> 1;
    int arow = bm + lrow;
    if (arow >= M) arow = M - 1;   // clamp loads; stores guarded below
    int ak = (tid & 1) * 4;
    int bk = tid >> 5;
    int bn = (tid & 31) * 4;
    int tm = (tid >> 4) * 8;
    int tn = (tid & 15) * 8;
    float acc[8][8];
    #pragma unroll
    for (int i = 0; i < 8; ++i)
        #pragma unroll
        for (int j = 0; j < 8; ++j) acc[i][j] = 0.f;

    for (int k0 = 0; k0 < 128; k0 += 8) {
        float4 av = *(const float4*)(A + (size_t)arow * 128 + k0 + ak);
        float4 bv = *(const float4*)(B + (size_t)(k0 + bk) * 128 + bn);
        __syncthreads();
        As[ak + 0][lrow] = av.x;
        As[ak + 1][lrow] = av.y;
        As[ak + 2][lrow] = av.z;
        As[ak + 3][lrow] = av.w;
        *(float4*)(&Bs[bk][bn]) = bv;
        __syncthreads();
        #pragma unroll
        for (int k = 0; k < 8; ++k) {
            float a[8], b[8];
            *(float4*)&a[0] = *(const float4*)&As[k][tm];
            *(float4*)&a[4] = *(const float4*)&As[k][tm + 4];
            *(float4*)&b[0] = *(const float4*)&Bs[k][tn];
            *(float4*)&b[4] = *(const float4*)&Bs[k][tn + 4];
            #pragma unroll
            for (int i = 0; i < 8; ++i)
                #pragma unroll
                for (int j = 0; j < 8; ++j)
                    acc[i][j] = fmaf(a[i], b[j], acc[i][j]);
        }
    }
    #pragma unroll
    for (int i = 0; i < 8; ++i) {
        int row = bm + tm + i;
        if (row < M) {
            float4 o0 = {acc[i][0], acc[i][1], acc[i][2], acc[i][3]};
            float4 o1 = {acc[i][4], acc[i][5], acc[i][6], acc[i][7]};
            *(float4*)(C + (size_t)row * 128 + tn) = o0;
            *(float4*)(C + (size_t)row * 128 + tn + 4) = o1;
        }
    }
}

// ---------------------------------------------------------------------------
// Edge logits: one wave per dst node; XR[dst] kept in registers across its
// incoming edges; lane handles 2 channels; per-head 16-lane shfl reduction.
// e[slot][h] written in CSR order.
// ---------------------------------------------------------------------------

__global__ __launch_bounds__(256) void edge_logits(const float* __restrict__ XL,
                                                   const float* __restrict__ XR,
                                                   const int* __restrict__ rp,
                                                   const int* __restrict__ csrc,
                                                   const float* __restrict__ att,
                                                   float* __restrict__ ebuf, int N) {
    int lane = threadIdx.x & 63;
    int node = blockIdx.x * 4 + (threadIdx.x >> 6);
    if (node >= N) return;
    int c0 = lane * 2;
    float2 a2 = *(const float2*)(att + c0);
    float2 xr = *(const float2*)(XR + (size_t)node * 128 + c0);
    int s = rp[node], e = rp[node + 1];
    for (int j = s; j < e; ++j) {
        int src = csrc[j];
        float2 xl = *(const float2*)(XL + (size_t)src * 128 + c0);
        float v0 = xl.x + xr.x; v0 = (v0 > 0.f) ? v0 : NEG_SLOPE * v0;
        float v1 = xl.y + xr.y; v1 = (v1 > 0.f) ? v1 : NEG_SLOPE * v1;
        float t = fmaf(v0, a2.x, v1 * a2.y);
        #pragma unroll
        for (int off = 1; off < 16; off <<= 1) t += __shfl_xor(t, off);
        if ((lane & 15) == 0) ebuf[(size_t)j * 4 + (lane >> 4)] = t;
    }
}

// Segment softmax: thread per (node, head); 3 short passes over its slots.
__global__ void softmax_edges(float* __restrict__ ebuf, const int* __restrict__ rp, int N) {
    int t = blockIdx.x * blockDim.x + threadIdx.x;
    int node = t >> 2;
    if (node >= N) return;
    int h = t & 3;
    int s = rp[node], e = rp[node + 1];
    if (s >= e) return;
    float m = -INFINITY;
    for (int j = s; j < e; ++j) m = fmaxf(m, ebuf[(size_t)j * 4 + h]);
    float sum = 0.f;
    for (int j = s; j < e; ++j) {
        float x = __expf(ebuf[(size_t)j * 4 + h] - m);
        ebuf[(size_t)j * 4 + h] = x;
        sum += x;
    }
    float inv = 1.f / (sum + SM_EPS);
    for (int j = s; j < e; ++j) ebuf[(size_t)j * 4 + h] *= inv;
}

// Aggregate: wave per dst node, atomic-free (+= into h pre-initialized with
// the summed relation biases; relations launched sequentially).
__global__ __launch_bounds__(256) void aggregate(const float* __restrict__ XL,
                                                 const float* __restrict__ ebuf,
                                                 const int* __restrict__ rp,
                                                 const int* __restrict__ csrc,
                                                 float* __restrict__ hout, int N) {
    int lane = threadIdx.x & 63;
    int node = blockIdx.x * 4 + (threadIdx.x >> 6);
    if (node >= N) return;
    int c0 = lane * 2;
    int hd = lane >> 4;
    int s = rp[node], e = rp[node + 1];
    float ax = 0.f, ay = 0.f;
    for (int j = s; j < e; ++j) {
        int src = csrc[j];
        float a = ebuf[(size_t)j * 4 + hd];
        float2 xl = *(const float2*)(XL + (size_t)src * 128 + c0);
        ax = fmaf(a, xl.x, ax);
        ay = fmaf(a, xl.y, ay);
    }
    float2* hp = (float2*)(hout + (size_t)node * 128 + c0);
    float2 o = *hp;
    o.x += ax; o.y += ay;
    *hp = o;
}

// h[i][c] = b[0][c] + b[1][c] + b[2][c]  (each conv adds its bias; sum of 3)
__global__ void init_h(float* __restrict__ h, const float* __restrict__ b3, int total4) {
    int t = blockIdx.x * blockDim.x + threadIdx.x;
    if (t < total4) {
        int c = (t & 31) * 4;
        float4 b0 = *(const float4*)(b3 + c);
        float4 b1 = *(const float4*)(b3 + 128 + c);
        float4 b2 = *(const float4*)(b3 + 256 + c);
        float4 o = {b0.x + b1.x + b2.x, b0.y + b1.y + b2.y,
                    b0.z + b1.z + b2.z, b0.w + b1.w + b2.w};
        *(float4*)(h + (size_t)t * 4) = o;
    }
}

// Final classifier: wave per game (4 nodes -> 512 features), relu, dot fcW.
__global__ __launch_bounds__(256) void final_fc(const float* __restrict__ h2,
                                                const float* __restrict__ fcW,
                                                const float* __restrict__ fcb,
                                                float* __restrict__ out, int G) {
    int lane = threadIdx.x & 63;
    int g = blockIdx.x * 4 + (threadIdx.x >> 6);
    if (g >= G) return;
    const float* hv = h2 + (size_t)g * 512 + lane * 8;
    float4 p0 = *(const float4*)hv;
    float4 p1 = *(const float4*)(hv + 4);
    float v[8] = {p0.x, p0.y, p0.z, p0.w, p1.x, p1.y, p1.z, p1.w};
    float acc0 = 0, acc1 = 0, acc2 = 0, acc3 = 0;
    #pragma unroll
    for (int jj = 0; jj < 8; ++jj) {
        float xv = v[jj] > 0.f ? v[jj] : 0.f;
        float4 w = *(const float4*)(fcW + (size_t)(lane * 8 + jj) * 4);
        acc0 = fmaf(xv, w.x, acc0);
        acc1 = fmaf(xv, w.y, acc1);
        acc2 = fmaf(xv, w.z, acc2);
        acc3 = fmaf(xv, w.w, acc3);
    }
    #pragma unroll
    for (int off = 1; off < 64; off <<= 1) {
        acc0 += __shfl_xor(acc0, off);
        acc1 += __shfl_xor(acc1, off);
        acc2 += __shfl_xor(acc2, off);
        acc3 += __shfl_xor(acc3, off);
    }
    if (lane == 0) {
        float4 o = {acc0 + fcb[0], acc1 + fcb[1], acc2 + fcb[2], acc3 + fcb[3]};
        *(float4*)(out + (size_t)g * 4) = o;
    }
}

// ---------------------------------------------------------------------------

extern "C" void kernel_launch(void* const* d_in, const int* in_sizes, int n_in,
                              void* d_out, int out_size, void* d_ws, size_t ws_size,
                              hipStream_t stream) {
    const float* x    = (const float*)d_in[0];
    const int*   e_f  = (const int*)d_in[1];
    const int*   e_a  = (const int*)d_in[2];
    const int*   e_v  = (const int*)d_in[3];
    const float* W1l  = (const float*)d_in[4];
    const float* W1r  = (const float*)d_in[5];
    const float* att1 = (const float*)d_in[6];
    const float* b1   = (const float*)d_in[7];
    const float* W2l  = (const float*)d_in[8];
    const float* W2r  = (const float*)d_in[9];
    const float* att2 = (const float*)d_in[10];
    const float* b2   = (const float*)d_in[11];
    const float* fcW  = (const float*)d_in[12];
    const float* fcb  = (const float*)d_in[13];
    float* out = (float*)d_out;

    int N = in_sizes[0] / 128;
    int E = in_sizes[1] / 2;

    // workspace carve (~110 MB total)
    char* ws = (char*)d_ws;
    size_t off = 0;
    auto alloc = [&](size_t bytes) -> void* {
        void* p = ws + off;
        off += (bytes + 255) & ~size_t(255);
        return p;
    };
    int*   deg3  = (int*)alloc((size_t)3 * N * 4);
    int*   cur3  = (int*)alloc((size_t)3 * N * 4);
    int*   rp3   = (int*)alloc((size_t)3 * (N + 1) * 4);
    int*   csrc3 = (int*)alloc((size_t)3 * E * 4);
    float* XL    = (float*)alloc((size_t)N * 128 * 4);
    float* XR    = (float*)alloc((size_t)N * 128 * 4);
    float* ebuf  = (float*)alloc((size_t)E * 4 * 4);
    float* h1    = (float*)alloc((size_t)N * 128 * 4);
    float* h2    = (float*)alloc((size_t)N * 128 * 4);

    const int* edges[3] = {e_f, e_a, e_v};

    // ---- CSR build (once; shared by both layers) ----
    hipMemsetAsync(deg3, 0, (size_t)3 * N * 4, stream);
    int ecb = (E + 255) / 256;
    for (int r = 0; r < 3; ++r)
        count_deg<<<ecb, 256, 0, stream>>>(edges[r], deg3 + (size_t)r * N, E);
    scan_deg<<<3, 1024, 0, stream>>>(deg3, rp3, cur3, N);
    for (int r = 0; r < 3; ++r)
        scatter_edges<<<ecb, 256, 0, stream>>>(edges[r], cur3 + (size_t)r * N,
                                               csrc3 + (size_t)r * E, E);

    int nb_rows  = (N + 127) / 128;
    int nb_node4 = (N + 3) / 4;
    int nb_nh    = (N * 4 + 255) / 256;
    int nb_init  = (N * 128 / 4 + 255) / 256;

    struct Layer {
        const float *in, *Wl, *Wr, *att, *b;
        float* hout;
    };
    Layer layers[2] = {
        { x,  W1l, W1r, att1, b1, h1 },
        { h1, W2l, W2r, att2, b2, h2 },
    };

    for (int L = 0; L < 2; ++L) {
        Layer& ly = layers[L];
        init_h<<<nb_init, 256, 0, stream>>>(ly.hout, ly.b, N * 128 / 4);
        for (int r = 0; r < 3; ++r) {
            gemm2<<<dim3(nb_rows, 2), 256, 0, stream>>>(
                ly.in, ly.Wl + (size_t)r * 128 * 128, ly.Wr + (size_t)r * 128 * 128,
                XL, XR, N);
            const int* rp   = rp3 + (size_t)r * (N + 1);
            const int* csrc = csrc3 + (size_t)r * E;
            edge_logits<<<nb_node4, 256, 0, stream>>>(XL, XR, rp, csrc,
                                                      ly.att + (size_t)r * 128, ebuf, N);
            softmax_edges<<<nb_nh, 256, 0, stream>>>(ebuf, rp, N);
            aggregate<<<nb_node4, 256, 0, stream>>>(XL, ebuf, rp, csrc, ly.hout, N);
        }
    }
    int G = N / 4;
    final_fc<<<(G + 3) / 4, 256, 0, stream>>>(h2, fcW, fcb, out, G);
}

// Round 5
// 1076.476 us; speedup vs baseline: 1.4190x; 1.4190x over previous
//
#include <hip/hip_runtime.h>
#include <hip/hip_bf16.h>
#include <math.h>

#define NEG_SLOPE 0.2f
#define SM_EPS 1e-16f

// ---------------------------------------------------------------------------
// CSR build: count degrees, exclusive-scan, scatter src ids grouped by dst.
// Edges are identical for layer 1 and layer 2, so we build CSR once per call.
// ---------------------------------------------------------------------------

__global__ void count_deg(const int* __restrict__ edge, int* __restrict__ deg, int E) {
    int t = blockIdx.x * blockDim.x + threadIdx.x;
    if (t < E) {
        int dst = edge[E + t];
        atomicAdd(&deg[dst], 1);
    }
}

// One block (1024 threads) per relation: sequential chunked scan over N values.
__global__ void scan_deg(const int* __restrict__ deg3, int* __restrict__ rp3,
                         int* __restrict__ cur3, int N) {
    int r = blockIdx.x;
    const int* deg = deg3 + (size_t)r * N;
    int* rp  = rp3 + (size_t)r * (N + 1);
    int* cur = cur3 + (size_t)r * N;
    __shared__ int wsum[16];
    __shared__ int total_s;
    int tid = threadIdx.x, lane = tid & 63, wid = tid >> 6;
    int carry = 0;
    for (int base = 0; base < N; base += 1024) {
        int i = base + tid;
        int v = (i < N) ? deg[i] : 0;
        int incl = v;
        #pragma unroll
        for (int off = 1; off < 64; off <<= 1) {
            int t2 = __shfl_up(incl, off);
            if (lane >= off) incl += t2;
        }
        if (lane == 63) wsum[wid] = incl;
        __syncthreads();
        if (wid == 0 && lane < 16) {
            int w = wsum[lane];
            int winc = w;
            #pragma unroll
            for (int off = 1; off < 16; off <<= 1) {
                int t2 = __shfl_up(winc, off);
                if (lane >= off) winc += t2;
            }
            wsum[lane] = winc - w;  // exclusive
            if (lane == 15) total_s = winc;
        }
        __syncthreads();
        int excl = carry + wsum[wid] + (incl - v);
        if (i < N) { rp[i] = excl; cur[i] = excl; }
        carry += total_s;
        __syncthreads();
    }
    if (tid == 0) rp[N] = carry;
}

__global__ void scatter_edges(const int* __restrict__ edge, int* __restrict__ cur,
                              int* __restrict__ csrc, int E) {
    int t = blockIdx.x * blockDim.x + threadIdx.x;
    if (t < E) {
        int src = edge[t];
        int dst = edge[E + t];
        int pos = atomicAdd(&cur[dst], 1);
        csrc[pos] = src;
    }
}

// ---------------------------------------------------------------------------
// Dual fp32 GEMM: C0 = A @ B0, C1 = A @ B1  (M x 128 @ 128 x 128).
// blockIdx.y selects (B0,C0) or (B1,C1). 128x128 tile per block, 8x8 per
// thread, K chunked by 8 through LDS (A stored k-major for broadcast reads).
// ---------------------------------------------------------------------------

__global__ __launch_bounds__(256) void gemm2(const float* __restrict__ A,
                                             const float* __restrict__ B0,
                                             const float* __restrict__ B1,
                                             float* __restrict__ C0,
                                             float* __restrict__ C1, int M) {
    const float* B = blockIdx.y ? B1 : B0;
    float* C = blockIdx.y ? C1 : C0;
    __shared__ float As[8][128];
    __shared__ float Bs[8][128];
    int tid = threadIdx.x;
    int bm = blockIdx.x * 128;
    int lrow = tid >> 1;
    int arow = bm + lrow;
    if (arow >= M) arow = M - 1;   // clamp loads; stores guarded below
    int ak = (tid & 1) * 4;
    int bk = tid >> 5;
    int bn = (tid & 31) * 4;
    int tm = (tid >> 4) * 8;
    int tn = (tid & 15) * 8;
    float acc[8][8];
    #pragma unroll
    for (int i = 0; i < 8; ++i)
        #pragma unroll
        for (int j = 0; j < 8; ++j) acc[i][j] = 0.f;

    for (int k0 = 0; k0 < 128; k0 += 8) {
        float4 av = *(const float4*)(A + (size_t)arow * 128 + k0 + ak);
        float4 bv = *(const float4*)(B + (size_t)(k0 + bk) * 128 + bn);
        __syncthreads();
        As[ak + 0][lrow] = av.x;
        As[ak + 1][lrow] = av.y;
        As[ak + 2][lrow] = av.z;
        As[ak + 3][lrow] = av.w;
        *(float4*)(&Bs[bk][bn]) = bv;
        __syncthreads();
        #pragma unroll
        for (int k = 0; k < 8; ++k) {
            float a[8], b[8];
            *(float4*)&a[0] = *(const float4*)&As[k][tm];
            *(float4*)&a[4] = *(const float4*)&As[k][tm + 4];
            *(float4*)&b[0] = *(const float4*)&Bs[k][tn];
            *(float4*)&b[4] = *(const float4*)&Bs[k][tn + 4];
            #pragma unroll
            for (int i = 0; i < 8; ++i)
                #pragma unroll
                for (int j = 0; j < 8; ++j)
                    acc[i][j] = fmaf(a[i], b[j], acc[i][j]);
        }
    }
    #pragma unroll
    for (int i = 0; i < 8; ++i) {
        int row = bm + tm + i;
        if (row < M) {
            float4 o0 = {acc[i][0], acc[i][1], acc[i][2], acc[i][3]};
            float4 o1 = {acc[i][4], acc[i][5], acc[i][6], acc[i][7]};
            *(float4*)(C + (size_t)row * 128 + tn) = o0;
            *(float4*)(C + (size_t)row * 128 + tn + 4) = o1;
        }
    }
}

// ---------------------------------------------------------------------------
// Fused edge pass (logits + segment-softmax + aggregate in ONE gather):
// one wave per dst node. XR[dst] and att live in registers. For each incoming
// edge, gather XL[src] once, compute the per-head logit via 16-lane shfl
// reduce, then do an online-softmax update (running max m, denom den, and
// rescaled weighted accumulator) entirely in registers. Finally scale by
// 1/(den+eps) and += into the bias-initialized hout. Atomic-free: relations
// are launched sequentially and each wave owns its node's output row.
// ---------------------------------------------------------------------------

__global__ __launch_bounds__(256) void edge_fused(const float* __restrict__ XL,
                                                  const float* __restrict__ XR,
                                                  const int* __restrict__ rp,
                                                  const int* __restrict__ csrc,
                                                  const float* __restrict__ att,
                                                  float* __restrict__ hout, int N) {
    int lane = threadIdx.x & 63;
    int node = blockIdx.x * 4 + (threadIdx.x >> 6);
    if (node >= N) return;
    int c0 = lane * 2;                       // 2 channels per lane; head = lane>>4
    float2 a2 = *(const float2*)(att + c0);
    float2 xr = *(const float2*)(XR + (size_t)node * 128 + c0);
    int s = rp[node], e = rp[node + 1];
    float m = -INFINITY, den = 0.f, ax = 0.f, ay = 0.f;
    for (int j = s; j < e; ++j) {
        int src = csrc[j];
        float2 xl = *(const float2*)(XL + (size_t)src * 128 + c0);
        float v0 = xl.x + xr.x; v0 = (v0 > 0.f) ? v0 : NEG_SLOPE * v0;
        float v1 = xl.y + xr.y; v1 = (v1 > 0.f) ? v1 : NEG_SLOPE * v1;
        float t = fmaf(v0, a2.x, v1 * a2.y);
        #pragma unroll
        for (int off = 1; off < 16; off <<= 1) t += __shfl_xor(t, off);
        // online softmax update (identical scalar state across the 16 lanes
        // of a head group; exp(-inf)=0 handles the first edge cleanly)
        float mnew = fmaxf(m, t);
        float scale = __expf(m - mnew);
        float p = __expf(t - mnew);
        den = fmaf(den, scale, p);
        ax  = fmaf(ax, scale, p * xl.x);
        ay  = fmaf(ay, scale, p * xl.y);
        m = mnew;
    }
    float inv = 1.f / (den + SM_EPS);        // matches PyG: alpha = ex/(denom+eps)
    float2* hp = (float2*)(hout + (size_t)node * 128 + c0);
    float2 o = *hp;
    o.x = fmaf(ax, inv, o.x);
    o.y = fmaf(ay, inv, o.y);
    *hp = o;
}

// h[i][c] = b[0][c] + b[1][c] + b[2][c]  (each conv adds its bias; sum of 3)
__global__ void init_h(float* __restrict__ h, const float* __restrict__ b3, int total4) {
    int t = blockIdx.x * blockDim.x + threadIdx.x;
    if (t < total4) {
        int c = (t & 31) * 4;
        float4 b0 = *(const float4*)(b3 + c);
        float4 b1 = *(const float4*)(b3 + 128 + c);
        float4 b2 = *(const float4*)(b3 + 256 + c);
        float4 o = {b0.x + b1.x + b2.x, b0.y + b1.y + b2.y,
                    b0.z + b1.z + b2.z, b0.w + b1.w + b2.w};
        *(float4*)(h + (size_t)t * 4) = o;
    }
}

// Final classifier: wave per game (4 nodes -> 512 features), relu, dot fcW.
__global__ __launch_bounds__(256) void final_fc(const float* __restrict__ h2,
                                                const float* __restrict__ fcW,
                                                const float* __restrict__ fcb,
                                                float* __restrict__ out, int G) {
    int lane = threadIdx.x & 63;
    int g = blockIdx.x * 4 + (threadIdx.x >> 6);
    if (g >= G) return;
    const float* hv = h2 + (size_t)g * 512 + lane * 8;
    float4 p0 = *(const float4*)hv;
    float4 p1 = *(const float4*)(hv + 4);
    float v[8] = {p0.x, p0.y, p0.z, p0.w, p1.x, p1.y, p1.z, p1.w};
    float acc0 = 0, acc1 = 0, acc2 = 0, acc3 = 0;
    #pragma unroll
    for (int jj = 0; jj < 8; ++jj) {
        float xv = v[jj] > 0.f ? v[jj] : 0.f;
        float4 w = *(const float4*)(fcW + (size_t)(lane * 8 + jj) * 4);
        acc0 = fmaf(xv, w.x, acc0);
        acc1 = fmaf(xv, w.y, acc1);
        acc2 = fmaf(xv, w.z, acc2);
        acc3 = fmaf(xv, w.w, acc3);
    }
    #pragma unroll
    for (int off = 1; off < 64; off <<= 1) {
        acc0 += __shfl_xor(acc0, off);
        acc1 += __shfl_xor(acc1, off);
        acc2 += __shfl_xor(acc2, off);
        acc3 += __shfl_xor(acc3, off);
    }
    if (lane == 0) {
        float4 o = {acc0 + fcb[0], acc1 + fcb[1], acc2 + fcb[2], acc3 + fcb[3]};
        *(float4*)(out + (size_t)g * 4) = o;
    }
}

// ---------------------------------------------------------------------------

extern "C" void kernel_launch(void* const* d_in, const int* in_sizes, int n_in,
                              void* d_out, int out_size, void* d_ws, size_t ws_size,
                              hipStream_t stream) {
    const float* x    = (const float*)d_in[0];
    const int*   e_f  = (const int*)d_in[1];
    const int*   e_a  = (const int*)d_in[2];
    const int*   e_v  = (const int*)d_in[3];
    const float* W1l  = (const float*)d_in[4];
    const float* W1r  = (const float*)d_in[5];
    const float* att1 = (const float*)d_in[6];
    const float* b1   = (const float*)d_in[7];
    const float* W2l  = (const float*)d_in[8];
    const float* W2r  = (const float*)d_in[9];
    const float* att2 = (const float*)d_in[10];
    const float* b2   = (const float*)d_in[11];
    const float* fcW  = (const float*)d_in[12];
    const float* fcb  = (const float*)d_in[13];
    float* out = (float*)d_out;

    int N = in_sizes[0] / 128;
    int E = in_sizes[1] / 2;

    // workspace carve (~102 MB total)
    char* ws = (char*)d_ws;
    size_t off = 0;
    auto alloc = [&](size_t bytes) -> void* {
        void* p = ws + off;
        off += (bytes + 255) & ~size_t(255);
        return p;
    };
    int*   deg3  = (int*)alloc((size_t)3 * N * 4);
    int*   cur3  = (int*)alloc((size_t)3 * N * 4);
    int*   rp3   = (int*)alloc((size_t)3 * (N + 1) * 4);
    int*   csrc3 = (int*)alloc((size_t)3 * E * 4);
    float* XL    = (float*)alloc((size_t)N * 128 * 4);
    float* XR    = (float*)alloc((size_t)N * 128 * 4);
    float* h1    = (float*)alloc((size_t)N * 128 * 4);
    float* h2    = (float*)alloc((size_t)N * 128 * 4);

    const int* edges[3] = {e_f, e_a, e_v};

    // ---- CSR build (once; shared by both layers) ----
    hipMemsetAsync(deg3, 0, (size_t)3 * N * 4, stream);
    int ecb = (E + 255) / 256;
    for (int r = 0; r < 3; ++r)
        count_deg<<<ecb, 256, 0, stream>>>(edges[r], deg3 + (size_t)r * N, E);
    scan_deg<<<3, 1024, 0, stream>>>(deg3, rp3, cur3, N);
    for (int r = 0; r < 3; ++r)
        scatter_edges<<<ecb, 256, 0, stream>>>(edges[r], cur3 + (size_t)r * N,
                                               csrc3 + (size_t)r * E, E);

    int nb_rows  = (N + 127) / 128;
    int nb_node4 = (N + 3) / 4;
    int nb_init  = (N * 128 / 4 + 255) / 256;

    struct Layer {
        const float *in, *Wl, *Wr, *att, *b;
        float* hout;
    };
    Layer layers[2] = {
        { x,  W1l, W1r, att1, b1, h1 },
        { h1, W2l, W2r, att2, b2, h2 },
    };

    for (int L = 0; L < 2; ++L) {
        Layer& ly = layers[L];
        init_h<<<nb_init, 256, 0, stream>>>(ly.hout, ly.b, N * 128 / 4);
        for (int r = 0; r < 3; ++r) {
            gemm2<<<dim3(nb_rows, 2), 256, 0, stream>>>(
                ly.in, ly.Wl + (size_t)r * 128 * 128, ly.Wr + (size_t)r * 128 * 128,
                XL, XR, N);
            const int* rp   = rp3 + (size_t)r * (N + 1);
            const int* csrc = csrc3 + (size_t)r * E;
            edge_fused<<<nb_node4, 256, 0, stream>>>(XL, XR, rp, csrc,
                                                     ly.att + (size_t)r * 128, ly.hout, N);
        }
    }
    int G = N / 4;
    final_fc<<<(G + 3) / 4, 256, 0, stream>>>(h2, fcW, fcb, out, G);
}

// Round 11
// 896.290 us; speedup vs baseline: 1.7043x; 1.2010x over previous
//
#include <hip/hip_runtime.h>
#include <hip/hip_bf16.h>
#include <math.h>

#define NEG_SLOPE 0.2f
#define SM_EPS 1e-16f

typedef short bf16x8 __attribute__((ext_vector_type(8)));
typedef float f32x16 __attribute__((ext_vector_type(16)));
typedef unsigned short ushort8 __attribute__((ext_vector_type(8)));
typedef unsigned short ushort4v __attribute__((ext_vector_type(4)));

__device__ inline unsigned short f2bf(float f) {
    unsigned int u = __float_as_uint(f);
    unsigned int r = (u + 0x7FFF + ((u >> 16) & 1)) >> 16;  // RNE
    return (unsigned short)r;
}

// ---------------------------------------------------------------------------
// CSR build: count degrees, exclusive-scan, scatter src ids grouped by dst.
// ---------------------------------------------------------------------------

__global__ void count_deg(const int* __restrict__ edge, int* __restrict__ deg, int E) {
    int t = blockIdx.x * blockDim.x + threadIdx.x;
    if (t < E) {
        int dst = edge[E + t];
        atomicAdd(&deg[dst], 1);
    }
}

__global__ void scan_deg(const int* __restrict__ deg3, int* __restrict__ rp3,
                         int* __restrict__ cur3, int N) {
    int r = blockIdx.x;
    const int* deg = deg3 + (size_t)r * N;
    int* rp  = rp3 + (size_t)r * (N + 1);
    int* cur = cur3 + (size_t)r * N;
    __shared__ int wsum[16];
    __shared__ int total_s;
    int tid = threadIdx.x, lane = tid & 63, wid = tid >> 6;
    int carry = 0;
    for (int base = 0; base < N; base += 1024) {
        int i = base + tid;
        int v = (i < N) ? deg[i] : 0;
        int incl = v;
        #pragma unroll
        for (int off = 1; off < 64; off <<= 1) {
            int t2 = __shfl_up(incl, off);
            if (lane >= off) incl += t2;
        }
        if (lane == 63) wsum[wid] = incl;
        __syncthreads();
        if (wid == 0 && lane < 16) {
            int w = wsum[lane];
            int winc = w;
            #pragma unroll
            for (int off = 1; off < 16; off <<= 1) {
                int t2 = __shfl_up(winc, off);
                if (lane >= off) winc += t2;
            }
            wsum[lane] = winc - w;  // exclusive
            if (lane == 15) total_s = winc;
        }
        __syncthreads();
        int excl = carry + wsum[wid] + (incl - v);
        if (i < N) { rp[i] = excl; cur[i] = excl; }
        carry += total_s;
        __syncthreads();
    }
    if (tid == 0) rp[N] = carry;
}

__global__ void scatter_edges(const int* __restrict__ edge, int* __restrict__ cur,
                              int* __restrict__ csrc, int E) {
    int t = blockIdx.x * blockDim.x + threadIdx.x;
    if (t < E) {
        int src = edge[t];
        int dst = edge[E + t];
        int pos = atomicAdd(&cur[dst], 1);
        csrc[pos] = src;
    }
}

// ---------------------------------------------------------------------------
// Precision staging: fp32 -> bf16 casts.
// cast_bf16: row-major activation table [M,128].
// transpose_cast_w: weights [g][r][k][c] fp32 -> WT [g*3+r][c][k] bf16
//   (transposed so the GEMM B-stage is a coalesced row read).
// ---------------------------------------------------------------------------

__global__ void cast_bf16(const float* __restrict__ in, unsigned short* __restrict__ out,
                          int n4) {
    int t = blockIdx.x * blockDim.x + threadIdx.x;
    if (t < n4) {
        float4 v = *(const float4*)(in + (size_t)t * 4);
        ushort4v o = {f2bf(v.x), f2bf(v.y), f2bf(v.z), f2bf(v.w)};
        *(ushort4v*)(out + (size_t)t * 4) = o;
    }
}

__global__ __launch_bounds__(256) void transpose_cast_w(
    const float* __restrict__ W1l, const float* __restrict__ W1r,
    const float* __restrict__ W2l, const float* __restrict__ W2r,
    unsigned short* __restrict__ WT) {
    const float* srcs[4] = {W1l, W1r, W2l, W2r};
    int g = blockIdx.z, r = blockIdx.y;
    const float* W = srcs[g] + (size_t)r * 16384;
    unsigned short* D = WT + (size_t)(g * 3 + r) * 16384;
    int t = blockIdx.x;                    // 16 tiles: 4x4 of 32x32
    int kr = (t >> 2) * 32, cb = (t & 3) * 32;
    __shared__ float tile[32][33];
    int tr = threadIdx.x >> 3, tc4 = (threadIdx.x & 7) * 4;
    float4 v = *(const float4*)(W + (size_t)(kr + tr) * 128 + cb + tc4);
    tile[tr][tc4 + 0] = v.x;
    tile[tr][tc4 + 1] = v.y;
    tile[tr][tc4 + 2] = v.z;
    tile[tr][tc4 + 3] = v.w;
    __syncthreads();
    int c = threadIdx.x >> 3, k4 = (threadIdx.x & 7) * 4;
    ushort4v o = {f2bf(tile[k4 + 0][c]), f2bf(tile[k4 + 1][c]),
                  f2bf(tile[k4 + 2][c]), f2bf(tile[k4 + 3][c])};
    *(ushort4v*)(D + (size_t)(cb + c) * 128 + kr + k4) = o;
}

// ---------------------------------------------------------------------------
// MFMA GEMM: C0 = A @ Wl, C1 = A @ Wr  (M x 128 @ 128 x 128, bf16 in, f32 out)
// grid (ceil(M/128), 4): y in {0,1} -> C0 col-half y; {2,3} -> C1 col-half y-2.
// Block: 256 thr = 4 waves (2x2). Per wave: 64 rows x 32 cols via
// v_mfma_f32_32x32x16_bf16, 8 K-steps, whole K=128 staged in LDS once.
// A-frag: row = lane&31, k = (lane>>5)*8 (contig 8). C/D: col = lane&31,
// row = (reg&3) + 8*(reg>>2) + 4*(lane>>5)   [measured m74/m101].
// LDS rows padded to 136 bf16 for bank spread.
// ---------------------------------------------------------------------------

__global__ __launch_bounds__(256) void gemm_mfma(
    const unsigned short* __restrict__ Abf,
    const unsigned short* __restrict__ WTl,
    const unsigned short* __restrict__ WTr,
    float* __restrict__ C0, float* __restrict__ C1, int M) {
    __shared__ unsigned short As[128][136];
    __shared__ unsigned short Bs[64][136];
    int tid = threadIdx.x;
    int bm = blockIdx.x * 128;
    int y = blockIdx.y;
    const unsigned short* WT = (y < 2 ? WTl : WTr) + (size_t)(y & 1) * 64 * 128;
    float* C = (y < 2) ? C0 : C1;
    int bcol = (y & 1) * 64;

    #pragma unroll
    for (int i = 0; i < 8; ++i) {            // A: 128 rows x 16 chunks
        int c = tid + i * 256;
        int row = c >> 4, ko = (c & 15) * 8;
        int gr = bm + row; if (gr >= M) gr = M - 1;
        ushort8 v = *(const ushort8*)(Abf + (size_t)gr * 128 + ko);
        *(ushort8*)(&As[row][ko]) = v;
    }
    #pragma unroll
    for (int i = 0; i < 4; ++i) {            // B^T: 64 rows x 16 chunks
        int c = tid + i * 256;
        int row = c >> 4, ko = (c & 15) * 8;
        ushort8 v = *(const ushort8*)(WT + (size_t)row * 128 + ko);
        *(ushort8*)(&Bs[row][ko]) = v;
    }
    __syncthreads();

    int wid = tid >> 6, lane = tid & 63;
    int wr = (wid >> 1) * 64, wc = (wid & 1) * 32;
    int la = lane & 31, lb = (lane >> 5) * 8;
    f32x16 acc0 = {};
    f32x16 acc1 = {};
    #pragma unroll
    for (int ks = 0; ks < 8; ++ks) {
        int k0 = ks * 16;
        bf16x8 a0 = *(const bf16x8*)(&As[wr + la][k0 + lb]);
        bf16x8 a1 = *(const bf16x8*)(&As[wr + 32 + la][k0 + lb]);
        bf16x8 b  = *(const bf16x8*)(&Bs[wc + la][k0 + lb]);
        acc0 = __builtin_amdgcn_mfma_f32_32x32x16_bf16(a0, b, acc0, 0, 0, 0);
        acc1 = __builtin_amdgcn_mfma_f32_32x32x16_bf16(a1, b, acc1, 0, 0, 0);
    }

    int col = bcol + wc + la;
    int rbase = (lane >> 5) * 4;
    #pragma unroll
    for (int reg = 0; reg < 16; ++reg) {
        int rr = (reg & 3) + 8 * (reg >> 2) + rbase;
        int row0 = bm + wr + rr;
        if (row0 < M) C[(size_t)row0 * 128 + col] = acc0[reg];
        int row1 = bm + wr + 32 + rr;
        if (row1 < M) C[(size_t)row1 * 128 + col] = acc1[reg];
    }
}

// ---------------------------------------------------------------------------
// Fused edge pass (logits + segment-softmax + aggregate), fp32, unchanged.
// ---------------------------------------------------------------------------

__global__ __launch_bounds__(256) void edge_fused(const float* __restrict__ XL,
                                                  const float* __restrict__ XR,
                                                  const int* __restrict__ rp,
                                                  const int* __restrict__ csrc,
                                                  const float* __restrict__ att,
                                                  float* __restrict__ hout, int N) {
    int lane = threadIdx.x & 63;
    int node = blockIdx.x * 4 + (threadIdx.x >> 6);
    if (node >= N) return;
    int c0 = lane * 2;                       // 2 channels per lane; head = lane>>4
    float2 a2 = *(const float2*)(att + c0);
    float2 xr = *(const float2*)(XR + (size_t)node * 128 + c0);
    int s = rp[node], e = rp[node + 1];
    float m = -INFINITY, den = 0.f, ax = 0.f, ay = 0.f;
    for (int j = s; j < e; ++j) {
        int src = csrc[j];
        float2 xl = *(const float2*)(XL + (size_t)src * 128 + c0);
        float v0 = xl.x + xr.x; v0 = (v0 > 0.f) ? v0 : NEG_SLOPE * v0;
        float v1 = xl.y + xr.y; v1 = (v1 > 0.f) ? v1 : NEG_SLOPE * v1;
        float t = fmaf(v0, a2.x, v1 * a2.y);
        #pragma unroll
        for (int off = 1; off < 16; off <<= 1) t += __shfl_xor(t, off);
        float mnew = fmaxf(m, t);
        float scale = __expf(m - mnew);
        float p = __expf(t - mnew);
        den = fmaf(den, scale, p);
        ax  = fmaf(ax, scale, p * xl.x);
        ay  = fmaf(ay, scale, p * xl.y);
        m = mnew;
    }
    float inv = 1.f / (den + SM_EPS);
    float2* hp = (float2*)(hout + (size_t)node * 128 + c0);
    float2 o = *hp;
    o.x = fmaf(ax, inv, o.x);
    o.y = fmaf(ay, inv, o.y);
    *hp = o;
}

// h[i][c] = b[0][c] + b[1][c] + b[2][c]
__global__ void init_h(float* __restrict__ h, const float* __restrict__ b3, int total4) {
    int t = blockIdx.x * blockDim.x + threadIdx.x;
    if (t < total4) {
        int c = (t & 31) * 4;
        float4 b0 = *(const float4*)(b3 + c);
        float4 b1 = *(const float4*)(b3 + 128 + c);
        float4 b2 = *(const float4*)(b3 + 256 + c);
        float4 o = {b0.x + b1.x + b2.x, b0.y + b1.y + b2.y,
                    b0.z + b1.z + b2.z, b0.w + b1.w + b2.w};
        *(float4*)(h + (size_t)t * 4) = o;
    }
}

// Final classifier: wave per game (4 nodes -> 512 features), relu, dot fcW.
__global__ __launch_bounds__(256) void final_fc(const float* __restrict__ h2,
                                                const float* __restrict__ fcW,
                                                const float* __restrict__ fcb,
                                                float* __restrict__ out, int G) {
    int lane = threadIdx.x & 63;
    int g = blockIdx.x * 4 + (threadIdx.x >> 6);
    if (g >= G) return;
    const float* hv = h2 + (size_t)g * 512 + lane * 8;
    float4 p0 = *(const float4*)hv;
    float4 p1 = *(const float4*)(hv + 4);
    float v[8] = {p0.x, p0.y, p0.z, p0.w, p1.x, p1.y, p1.z, p1.w};
    float acc0 = 0, acc1 = 0, acc2 = 0, acc3 = 0;
    #pragma unroll
    for (int jj = 0; jj < 8; ++jj) {
        float xv = v[jj] > 0.f ? v[jj] : 0.f;
        float4 w = *(const float4*)(fcW + (size_t)(lane * 8 + jj) * 4);
        acc0 = fmaf(xv, w.x, acc0);
        acc1 = fmaf(xv, w.y, acc1);
        acc2 = fmaf(xv, w.z, acc2);
        acc3 = fmaf(xv, w.w, acc3);
    }
    #pragma unroll
    for (int off = 1; off < 64; off <<= 1) {
        acc0 += __shfl_xor(acc0, off);
        acc1 += __shfl_xor(acc1, off);
        acc2 += __shfl_xor(acc2, off);
        acc3 += __shfl_xor(acc3, off);
    }
    if (lane == 0) {
        float4 o = {acc0 + fcb[0], acc1 + fcb[1], acc2 + fcb[2], acc3 + fcb[3]};
        *(float4*)(out + (size_t)g * 4) = o;
    }
}

// ---------------------------------------------------------------------------

extern "C" void kernel_launch(void* const* d_in, const int* in_sizes, int n_in,
                              void* d_out, int out_size, void* d_ws, size_t ws_size,
                              hipStream_t stream) {
    const float* x    = (const float*)d_in[0];
    const int*   e_f  = (const int*)d_in[1];
    const int*   e_a  = (const int*)d_in[2];
    const int*   e_v  = (const int*)d_in[3];
    const float* W1l  = (const float*)d_in[4];
    const float* W1r  = (const float*)d_in[5];
    const float* att1 = (const float*)d_in[6];
    const float* b1   = (const float*)d_in[7];
    const float* W2l  = (const float*)d_in[8];
    const float* W2r  = (const float*)d_in[9];
    const float* att2 = (const float*)d_in[10];
    const float* b2   = (const float*)d_in[11];
    const float* fcW  = (const float*)d_in[12];
    const float* fcb  = (const float*)d_in[13];
    float* out = (float*)d_out;

    int N = in_sizes[0] / 128;
    int E = in_sizes[1] / 2;

    // workspace carve (~124 MB total)
    char* ws = (char*)d_ws;
    size_t off = 0;
    auto alloc = [&](size_t bytes) -> void* {
        void* p = ws + off;
        off += (bytes + 255) & ~size_t(255);
        return p;
    };
    int*   deg3  = (int*)alloc((size_t)3 * N * 4);
    int*   cur3  = (int*)alloc((size_t)3 * N * 4);
    int*   rp3   = (int*)alloc((size_t)3 * (N + 1) * 4);
    int*   csrc3 = (int*)alloc((size_t)3 * E * 4);
    float* XL    = (float*)alloc((size_t)N * 128 * 4);
    float* XR    = (float*)alloc((size_t)N * 128 * 4);
    float* h1    = (float*)alloc((size_t)N * 128 * 4);
    float* h2    = (float*)alloc((size_t)N * 128 * 4);
    unsigned short* Abf = (unsigned short*)alloc((size_t)N * 128 * 2);
    unsigned short* WT  = (unsigned short*)alloc((size_t)12 * 128 * 128 * 2);

    const int* edges[3] = {e_f, e_a, e_v};

    // ---- CSR build (once; shared by both layers) ----
    hipMemsetAsync(deg3, 0, (size_t)3 * N * 4, stream);
    int ecb = (E + 255) / 256;
    for (int r = 0; r < 3; ++r)
        count_deg<<<ecb, 256, 0, stream>>>(edges[r], deg3 + (size_t)r * N, E);
    scan_deg<<<3, 1024, 0, stream>>>(deg3, rp3, cur3, N);
    for (int r = 0; r < 3; ++r)
        scatter_edges<<<ecb, 256, 0, stream>>>(edges[r], cur3 + (size_t)r * N,
                                               csrc3 + (size_t)r * E, E);

    // ---- weights -> bf16 transposed (once) ----
    transpose_cast_w<<<dim3(16, 3, 4), 256, 0, stream>>>(W1l, W1r, W2l, W2r, WT);

    int nb_rows  = (N + 127) / 128;
    int nb_node4 = (N + 3) / 4;
    int nb_init  = (N * 128 / 4 + 255) / 256;
    int nb_cast  = (N * 128 / 4 + 255) / 256;

    struct Layer {
        const float *in, *att, *b;
        int wtg_l, wtg_r;   // WT group indices (x3 relations each)
        float* hout;
    };
    Layer layers[2] = {
        { x,  att1, b1, 0, 1, h1 },
        { h1, att2, b2, 2, 3, h2 },
    };

    for (int L = 0; L < 2; ++L) {
        Layer& ly = layers[L];
        cast_bf16<<<nb_cast, 256, 0, stream>>>(ly.in, Abf, N * 128 / 4);
        init_h<<<nb_init, 256, 0, stream>>>(ly.hout, ly.b, N * 128 / 4);
        for (int r = 0; r < 3; ++r) {
            const unsigned short* WTl = WT + (size_t)(ly.wtg_l * 3 + r) * 16384;
            const unsigned short* WTr = WT + (size_t)(ly.wtg_r * 3 + r) * 16384;
            gemm_mfma<<<dim3(nb_rows, 4), 256, 0, stream>>>(Abf, WTl, WTr, XL, XR, N);
            const int* rp   = rp3 + (size_t)r * (N + 1);
            const int* csrc = csrc3 + (size_t)r * E;
            edge_fused<<<nb_node4, 256, 0, stream>>>(XL, XR, rp, csrc,
                                                     ly.att + (size_t)r * 128, ly.hout, N);
        }
    }
    int G = N / 4;
    final_fc<<<(G + 3) / 4, 256, 0, stream>>>(h2, fcW, fcb, out, G);
}

// Round 12
// 842.538 us; speedup vs baseline: 1.8131x; 1.0638x over previous
//
#include <hip/hip_runtime.h>
#include <hip/hip_bf16.h>
#include <math.h>

#define NEG_SLOPE 0.2f
#define SM_EPS 1e-16f

typedef short bf16x8 __attribute__((ext_vector_type(8)));
typedef float f32x16 __attribute__((ext_vector_type(16)));
typedef unsigned short ushort8 __attribute__((ext_vector_type(8)));
typedef unsigned short ushort4v __attribute__((ext_vector_type(4)));

__device__ inline unsigned short f2bf(float f) {
    unsigned int u = __float_as_uint(f);
    unsigned int r = (u + 0x7FFF + ((u >> 16) & 1)) >> 16;  // RNE
    return (unsigned short)r;
}

// ---------------------------------------------------------------------------
// CSR build: count degrees, exclusive-scan, scatter src ids grouped by dst.
// ---------------------------------------------------------------------------

__global__ void count_deg(const int* __restrict__ edge, int* __restrict__ deg, int E) {
    int t = blockIdx.x * blockDim.x + threadIdx.x;
    if (t < E) {
        int dst = edge[E + t];
        atomicAdd(&deg[dst], 1);
    }
}

__global__ void scan_deg(const int* __restrict__ deg3, int* __restrict__ rp3,
                         int* __restrict__ cur3, int N) {
    int r = blockIdx.x;
    const int* deg = deg3 + (size_t)r * N;
    int* rp  = rp3 + (size_t)r * (N + 1);
    int* cur = cur3 + (size_t)r * N;
    __shared__ int wsum[16];
    __shared__ int total_s;
    int tid = threadIdx.x, lane = tid & 63, wid = tid >> 6;
    int carry = 0;
    for (int base = 0; base < N; base += 1024) {
        int i = base + tid;
        int v = (i < N) ? deg[i] : 0;
        int incl = v;
        #pragma unroll
        for (int off = 1; off < 64; off <<= 1) {
            int t2 = __shfl_up(incl, off);
            if (lane >= off) incl += t2;
        }
        if (lane == 63) wsum[wid] = incl;
        __syncthreads();
        if (wid == 0 && lane < 16) {
            int w = wsum[lane];
            int winc = w;
            #pragma unroll
            for (int off = 1; off < 16; off <<= 1) {
                int t2 = __shfl_up(winc, off);
                if (lane >= off) winc += t2;
            }
            wsum[lane] = winc - w;  // exclusive
            if (lane == 15) total_s = winc;
        }
        __syncthreads();
        int excl = carry + wsum[wid] + (incl - v);
        if (i < N) { rp[i] = excl; cur[i] = excl; }
        carry += total_s;
        __syncthreads();
    }
    if (tid == 0) rp[N] = carry;
}

__global__ void scatter_edges(const int* __restrict__ edge, int* __restrict__ cur,
                              int* __restrict__ csrc, int E) {
    int t = blockIdx.x * blockDim.x + threadIdx.x;
    if (t < E) {
        int src = edge[t];
        int dst = edge[E + t];
        int pos = atomicAdd(&cur[dst], 1);
        csrc[pos] = src;
    }
}

// ---------------------------------------------------------------------------
// Precision staging: fp32 -> bf16 casts.
// ---------------------------------------------------------------------------

__global__ void cast_bf16(const float* __restrict__ in, unsigned short* __restrict__ out,
                          int n4) {
    int t = blockIdx.x * blockDim.x + threadIdx.x;
    if (t < n4) {
        float4 v = *(const float4*)(in + (size_t)t * 4);
        ushort4v o = {f2bf(v.x), f2bf(v.y), f2bf(v.z), f2bf(v.w)};
        *(ushort4v*)(out + (size_t)t * 4) = o;
    }
}

__global__ __launch_bounds__(256) void transpose_cast_w(
    const float* __restrict__ W1l, const float* __restrict__ W1r,
    const float* __restrict__ W2l, const float* __restrict__ W2r,
    unsigned short* __restrict__ WT) {
    const float* srcs[4] = {W1l, W1r, W2l, W2r};
    int g = blockIdx.z, r = blockIdx.y;
    const float* W = srcs[g] + (size_t)r * 16384;
    unsigned short* D = WT + (size_t)(g * 3 + r) * 16384;
    int t = blockIdx.x;                    // 16 tiles: 4x4 of 32x32
    int kr = (t >> 2) * 32, cb = (t & 3) * 32;
    __shared__ float tile[32][33];
    int tr = threadIdx.x >> 3, tc4 = (threadIdx.x & 7) * 4;
    float4 v = *(const float4*)(W + (size_t)(kr + tr) * 128 + cb + tc4);
    tile[tr][tc4 + 0] = v.x;
    tile[tr][tc4 + 1] = v.y;
    tile[tr][tc4 + 2] = v.z;
    tile[tr][tc4 + 3] = v.w;
    __syncthreads();
    int c = threadIdx.x >> 3, k4 = (threadIdx.x & 7) * 4;
    ushort4v o = {f2bf(tile[k4 + 0][c]), f2bf(tile[k4 + 1][c]),
                  f2bf(tile[k4 + 2][c]), f2bf(tile[k4 + 3][c])};
    *(ushort4v*)(D + (size_t)(cb + c) * 128 + kr + k4) = o;
}

// ---------------------------------------------------------------------------
// MFMA GEMM: C0 = A @ Wl, C1 = A @ Wr  (M x 128 @ 128 x 128, bf16 in,
// *** bf16 out *** — XL/XR staging tables are now bf16, halving both the
// GEMM C-write traffic and the edge-phase gather traffic).
// Layouts unchanged (m74/m101-verified). LDS rows padded to 136.
// ---------------------------------------------------------------------------

__global__ __launch_bounds__(256) void gemm_mfma(
    const unsigned short* __restrict__ Abf,
    const unsigned short* __restrict__ WTl,
    const unsigned short* __restrict__ WTr,
    unsigned short* __restrict__ C0, unsigned short* __restrict__ C1, int M) {
    __shared__ unsigned short As[128][136];
    __shared__ unsigned short Bs[64][136];
    int tid = threadIdx.x;
    int bm = blockIdx.x * 128;
    int y = blockIdx.y;
    const unsigned short* WT = (y < 2 ? WTl : WTr) + (size_t)(y & 1) * 64 * 128;
    unsigned short* C = (y < 2) ? C0 : C1;
    int bcol = (y & 1) * 64;

    #pragma unroll
    for (int i = 0; i < 8; ++i) {            // A: 128 rows x 16 chunks
        int c = tid + i * 256;
        int row = c >> 4, ko = (c & 15) * 8;
        int gr = bm + row; if (gr >= M) gr = M - 1;
        ushort8 v = *(const ushort8*)(Abf + (size_t)gr * 128 + ko);
        *(ushort8*)(&As[row][ko]) = v;
    }
    #pragma unroll
    for (int i = 0; i < 4; ++i) {            // B^T: 64 rows x 16 chunks
        int c = tid + i * 256;
        int row = c >> 4, ko = (c & 15) * 8;
        ushort8 v = *(const ushort8*)(WT + (size_t)row * 128 + ko);
        *(ushort8*)(&Bs[row][ko]) = v;
    }
    __syncthreads();

    int wid = tid >> 6, lane = tid & 63;
    int wr = (wid >> 1) * 64, wc = (wid & 1) * 32;
    int la = lane & 31, lb = (lane >> 5) * 8;
    f32x16 acc0 = {};
    f32x16 acc1 = {};
    #pragma unroll
    for (int ks = 0; ks < 8; ++ks) {
        int k0 = ks * 16;
        bf16x8 a0 = *(const bf16x8*)(&As[wr + la][k0 + lb]);
        bf16x8 a1 = *(const bf16x8*)(&As[wr + 32 + la][k0 + lb]);
        bf16x8 b  = *(const bf16x8*)(&Bs[wc + la][k0 + lb]);
        acc0 = __builtin_amdgcn_mfma_f32_32x32x16_bf16(a0, b, acc0, 0, 0, 0);
        acc1 = __builtin_amdgcn_mfma_f32_32x32x16_bf16(a1, b, acc1, 0, 0, 0);
    }

    int col = bcol + wc + la;
    int rbase = (lane >> 5) * 4;
    #pragma unroll
    for (int reg = 0; reg < 16; ++reg) {
        int rr = (reg & 3) + 8 * (reg >> 2) + rbase;
        int row0 = bm + wr + rr;
        if (row0 < M) C[(size_t)row0 * 128 + col] = f2bf(acc0[reg]);
        int row1 = bm + wr + 32 + rr;
        if (row1 < M) C[(size_t)row1 * 128 + col] = f2bf(acc1[reg]);
    }
}

// ---------------------------------------------------------------------------
// Fused edge pass (logits + segment-softmax + aggregate). XL/XR are bf16
// tables read as one uint (2 channels) per lane; all math stays fp32.
// ---------------------------------------------------------------------------

__global__ __launch_bounds__(256) void edge_fused(const unsigned int* __restrict__ XL2,
                                                  const unsigned int* __restrict__ XR2,
                                                  const int* __restrict__ rp,
                                                  const int* __restrict__ csrc,
                                                  const float* __restrict__ att,
                                                  float* __restrict__ hout, int N) {
    int lane = threadIdx.x & 63;
    int node = blockIdx.x * 4 + (threadIdx.x >> 6);
    if (node >= N) return;
    int c0 = lane * 2;                       // 2 channels per lane; head = lane>>4
    float2 a2 = *(const float2*)(att + c0);
    unsigned int xru = XR2[(size_t)node * 64 + lane];
    float xrx = __uint_as_float(xru << 16);
    float xry = __uint_as_float(xru & 0xFFFF0000u);
    int s = rp[node], e = rp[node + 1];
    float m = -INFINITY, den = 0.f, ax = 0.f, ay = 0.f;
    for (int j = s; j < e; ++j) {
        int src = csrc[j];
        unsigned int xlu = XL2[(size_t)src * 64 + lane];
        float xlx = __uint_as_float(xlu << 16);
        float xly = __uint_as_float(xlu & 0xFFFF0000u);
        float v0 = xlx + xrx; v0 = (v0 > 0.f) ? v0 : NEG_SLOPE * v0;
        float v1 = xly + xry; v1 = (v1 > 0.f) ? v1 : NEG_SLOPE * v1;
        float t = fmaf(v0, a2.x, v1 * a2.y);
        #pragma unroll
        for (int off = 1; off < 16; off <<= 1) t += __shfl_xor(t, off);
        float mnew = fmaxf(m, t);
        float scale = __expf(m - mnew);
        float p = __expf(t - mnew);
        den = fmaf(den, scale, p);
        ax  = fmaf(ax, scale, p * xlx);
        ay  = fmaf(ay, scale, p * xly);
        m = mnew;
    }
    float inv = 1.f / (den + SM_EPS);
    float2* hp = (float2*)(hout + (size_t)node * 128 + c0);
    float2 o = *hp;
    o.x = fmaf(ax, inv, o.x);
    o.y = fmaf(ay, inv, o.y);
    *hp = o;
}

// h[i][c] = b[0][c] + b[1][c] + b[2][c]
__global__ void init_h(float* __restrict__ h, const float* __restrict__ b3, int total4) {
    int t = blockIdx.x * blockDim.x + threadIdx.x;
    if (t < total4) {
        int c = (t & 31) * 4;
        float4 b0 = *(const float4*)(b3 + c);
        float4 b1 = *(const float4*)(b3 + 128 + c);
        float4 b2 = *(const float4*)(b3 + 256 + c);
        float4 o = {b0.x + b1.x + b2.x, b0.y + b1.y + b2.y,
                    b0.z + b1.z + b2.z, b0.w + b1.w + b2.w};
        *(float4*)(h + (size_t)t * 4) = o;
    }
}

// Final classifier: wave per game (4 nodes -> 512 features), relu, dot fcW.
__global__ __launch_bounds__(256) void final_fc(const float* __restrict__ h2,
                                                const float* __restrict__ fcW,
                                                const float* __restrict__ fcb,
                                                float* __restrict__ out, int G) {
    int lane = threadIdx.x & 63;
    int g = blockIdx.x * 4 + (threadIdx.x >> 6);
    if (g >= G) return;
    const float* hv = h2 + (size_t)g * 512 + lane * 8;
    float4 p0 = *(const float4*)hv;
    float4 p1 = *(const float4*)(hv + 4);
    float v[8] = {p0.x, p0.y, p0.z, p0.w, p1.x, p1.y, p1.z, p1.w};
    float acc0 = 0, acc1 = 0, acc2 = 0, acc3 = 0;
    #pragma unroll
    for (int jj = 0; jj < 8; ++jj) {
        float xv = v[jj] > 0.f ? v[jj] : 0.f;
        float4 w = *(const float4*)(fcW + (size_t)(lane * 8 + jj) * 4);
        acc0 = fmaf(xv, w.x, acc0);
        acc1 = fmaf(xv, w.y, acc1);
        acc2 = fmaf(xv, w.z, acc2);
        acc3 = fmaf(xv, w.w, acc3);
    }
    #pragma unroll
    for (int off = 1; off < 64; off <<= 1) {
        acc0 += __shfl_xor(acc0, off);
        acc1 += __shfl_xor(acc1, off);
        acc2 += __shfl_xor(acc2, off);
        acc3 += __shfl_xor(acc3, off);
    }
    if (lane == 0) {
        float4 o = {acc0 + fcb[0], acc1 + fcb[1], acc2 + fcb[2], acc3 + fcb[3]};
        *(float4*)(out + (size_t)g * 4) = o;
    }
}

// ---------------------------------------------------------------------------

extern "C" void kernel_launch(void* const* d_in, const int* in_sizes, int n_in,
                              void* d_out, int out_size, void* d_ws, size_t ws_size,
                              hipStream_t stream) {
    const float* x    = (const float*)d_in[0];
    const int*   e_f  = (const int*)d_in[1];
    const int*   e_a  = (const int*)d_in[2];
    const int*   e_v  = (const int*)d_in[3];
    const float* W1l  = (const float*)d_in[4];
    const float* W1r  = (const float*)d_in[5];
    const float* att1 = (const float*)d_in[6];
    const float* b1   = (const float*)d_in[7];
    const float* W2l  = (const float*)d_in[8];
    const float* W2r  = (const float*)d_in[9];
    const float* att2 = (const float*)d_in[10];
    const float* b2   = (const float*)d_in[11];
    const float* fcW  = (const float*)d_in[12];
    const float* fcb  = (const float*)d_in[13];
    float* out = (float*)d_out;

    int N = in_sizes[0] / 128;
    int E = in_sizes[1] / 2;

    // workspace carve (~100 MB total)
    char* ws = (char*)d_ws;
    size_t off = 0;
    auto alloc = [&](size_t bytes) -> void* {
        void* p = ws + off;
        off += (bytes + 255) & ~size_t(255);
        return p;
    };
    int*   deg3  = (int*)alloc((size_t)3 * N * 4);
    int*   cur3  = (int*)alloc((size_t)3 * N * 4);
    int*   rp3   = (int*)alloc((size_t)3 * (N + 1) * 4);
    int*   csrc3 = (int*)alloc((size_t)3 * E * 4);
    unsigned short* XLbf = (unsigned short*)alloc((size_t)N * 128 * 2);
    unsigned short* XRbf = (unsigned short*)alloc((size_t)N * 128 * 2);
    float* h1    = (float*)alloc((size_t)N * 128 * 4);
    float* h2    = (float*)alloc((size_t)N * 128 * 4);
    unsigned short* Abf = (unsigned short*)alloc((size_t)N * 128 * 2);
    unsigned short* WT  = (unsigned short*)alloc((size_t)12 * 128 * 128 * 2);

    const int* edges[3] = {e_f, e_a, e_v};

    // ---- CSR build (once; shared by both layers) ----
    hipMemsetAsync(deg3, 0, (size_t)3 * N * 4, stream);
    int ecb = (E + 255) / 256;
    for (int r = 0; r < 3; ++r)
        count_deg<<<ecb, 256, 0, stream>>>(edges[r], deg3 + (size_t)r * N, E);
    scan_deg<<<3, 1024, 0, stream>>>(deg3, rp3, cur3, N);
    for (int r = 0; r < 3; ++r)
        scatter_edges<<<ecb, 256, 0, stream>>>(edges[r], cur3 + (size_t)r * N,
                                               csrc3 + (size_t)r * E, E);

    // ---- weights -> bf16 transposed (once) ----
    transpose_cast_w<<<dim3(16, 3, 4), 256, 0, stream>>>(W1l, W1r, W2l, W2r, WT);

    int nb_rows  = (N + 127) / 128;
    int nb_node4 = (N + 3) / 4;
    int nb_init  = (N * 128 / 4 + 255) / 256;
    int nb_cast  = (N * 128 / 4 + 255) / 256;

    struct Layer {
        const float *in, *att, *b;
        int wtg_l, wtg_r;   // WT group indices (x3 relations each)
        float* hout;
    };
    Layer layers[2] = {
        { x,  att1, b1, 0, 1, h1 },
        { h1, att2, b2, 2, 3, h2 },
    };

    for (int L = 0; L < 2; ++L) {
        Layer& ly = layers[L];
        cast_bf16<<<nb_cast, 256, 0, stream>>>(ly.in, Abf, N * 128 / 4);
        init_h<<<nb_init, 256, 0, stream>>>(ly.hout, ly.b, N * 128 / 4);
        for (int r = 0; r < 3; ++r) {
            const unsigned short* WTl = WT + (size_t)(ly.wtg_l * 3 + r) * 16384;
            const unsigned short* WTr = WT + (size_t)(ly.wtg_r * 3 + r) * 16384;
            gemm_mfma<<<dim3(nb_rows, 4), 256, 0, stream>>>(Abf, WTl, WTr, XLbf, XRbf, N);
            const int* rp   = rp3 + (size_t)r * (N + 1);
            const int* csrc = csrc3 + (size_t)r * E;
            edge_fused<<<nb_node4, 256, 0, stream>>>((const unsigned int*)XLbf,
                                                     (const unsigned int*)XRbf, rp, csrc,
                                                     ly.att + (size_t)r * 128, ly.hout, N);
        }
    }
    int G = N / 4;
    final_fc<<<(G + 3) / 4, 256, 0, stream>>>(h2, fcW, fcb, out, G);
}

// Round 14
// 662.557 us; speedup vs baseline: 2.3056x; 1.2716x over previous
//
#include <hip/hip_runtime.h>
#include <hip/hip_bf16.h>
#include <math.h>

#define NEG_SLOPE 0.2f
#define SM_EPS 1e-16f

typedef short bf16x8 __attribute__((ext_vector_type(8)));
typedef float f32x16 __attribute__((ext_vector_type(16)));
typedef unsigned short ushort8 __attribute__((ext_vector_type(8)));
typedef unsigned short ushort4v __attribute__((ext_vector_type(4)));

__device__ inline unsigned short f2bf(float f) {
    unsigned int u = __float_as_uint(f);
    unsigned int r = (u + 0x7FFF + ((u >> 16) & 1)) >> 16;  // RNE
    return (unsigned short)r;
}

// ---------------------------------------------------------------------------
// CSR build: count degrees, exclusive-scan, scatter src ids grouped by dst.
// ---------------------------------------------------------------------------

__global__ void count_deg(const int* __restrict__ edge, int* __restrict__ deg, int E) {
    int t = blockIdx.x * blockDim.x + threadIdx.x;
    if (t < E) {
        int dst = edge[E + t];
        atomicAdd(&deg[dst], 1);
    }
}

__global__ void scan_deg(const int* __restrict__ deg3, int* __restrict__ rp3,
                         int* __restrict__ cur3, int N) {
    int r = blockIdx.x;
    const int* deg = deg3 + (size_t)r * N;
    int* rp  = rp3 + (size_t)r * (N + 1);
    int* cur = cur3 + (size_t)r * N;
    __shared__ int wsum[16];
    __shared__ int total_s;
    int tid = threadIdx.x, lane = tid & 63, wid = tid >> 6;
    int carry = 0;
    for (int base = 0; base < N; base += 1024) {
        int i = base + tid;
        int v = (i < N) ? deg[i] : 0;
        int incl = v;
        #pragma unroll
        for (int off = 1; off < 64; off <<= 1) {
            int t2 = __shfl_up(incl, off);
            if (lane >= off) incl += t2;
        }
        if (lane == 63) wsum[wid] = incl;
        __syncthreads();
        if (wid == 0 && lane < 16) {
            int w = wsum[lane];
            int winc = w;
            #pragma unroll
            for (int off = 1; off < 16; off <<= 1) {
                int t2 = __shfl_up(winc, off);
                if (lane >= off) winc += t2;
            }
            wsum[lane] = winc - w;  // exclusive
            if (lane == 15) total_s = winc;
        }
        __syncthreads();
        int excl = carry + wsum[wid] + (incl - v);
        if (i < N) { rp[i] = excl; cur[i] = excl; }
        carry += total_s;
        __syncthreads();
    }
    if (tid == 0) rp[N] = carry;
}

__global__ void scatter_edges(const int* __restrict__ edge, int* __restrict__ cur,
                              int* __restrict__ csrc, int E) {
    int t = blockIdx.x * blockDim.x + threadIdx.x;
    if (t < E) {
        int src = edge[t];
        int dst = edge[E + t];
        int pos = atomicAdd(&cur[dst], 1);
        csrc[pos] = src;
    }
}

// ---------------------------------------------------------------------------
// Precision staging: fp32 -> bf16 casts.
// ---------------------------------------------------------------------------

__global__ void cast_bf16(const float* __restrict__ in, unsigned short* __restrict__ out,
                          int n4) {
    int t = blockIdx.x * blockDim.x + threadIdx.x;
    if (t < n4) {
        float4 v = *(const float4*)(in + (size_t)t * 4);
        ushort4v o = {f2bf(v.x), f2bf(v.y), f2bf(v.z), f2bf(v.w)};
        *(ushort4v*)(out + (size_t)t * 4) = o;
    }
}

__global__ __launch_bounds__(256) void transpose_cast_w(
    const float* __restrict__ W1l, const float* __restrict__ W1r,
    const float* __restrict__ W2l, const float* __restrict__ W2r,
    unsigned short* __restrict__ WT) {
    const float* srcs[4] = {W1l, W1r, W2l, W2r};
    int g = blockIdx.z, r = blockIdx.y;
    const float* W = srcs[g] + (size_t)r * 16384;
    unsigned short* D = WT + (size_t)(g * 3 + r) * 16384;
    int t = blockIdx.x;                    // 16 tiles: 4x4 of 32x32
    int kr = (t >> 2) * 32, cb = (t & 3) * 32;
    __shared__ float tile[32][33];
    int tr = threadIdx.x >> 3, tc4 = (threadIdx.x & 7) * 4;
    float4 v = *(const float4*)(W + (size_t)(kr + tr) * 128 + cb + tc4);
    tile[tr][tc4 + 0] = v.x;
    tile[tr][tc4 + 1] = v.y;
    tile[tr][tc4 + 2] = v.z;
    tile[tr][tc4 + 3] = v.w;
    __syncthreads();
    int c = threadIdx.x >> 3, k4 = (threadIdx.x & 7) * 4;
    ushort4v o = {f2bf(tile[k4 + 0][c]), f2bf(tile[k4 + 1][c]),
                  f2bf(tile[k4 + 2][c]), f2bf(tile[k4 + 3][c])};
    *(ushort4v*)(D + (size_t)(cb + c) * 128 + kr + k4) = o;
}

// ---------------------------------------------------------------------------
// MFMA GEMM: C0 = A @ Wl, C1 = A @ Wr  (M x 128 @ 128 x 128, bf16 in/out).
// Layouts unchanged (m74/m101-verified). LDS rows padded to 136.
// ---------------------------------------------------------------------------

__global__ __launch_bounds__(256) void gemm_mfma(
    const unsigned short* __restrict__ Abf,
    const unsigned short* __restrict__ WTl,
    const unsigned short* __restrict__ WTr,
    unsigned short* __restrict__ C0, unsigned short* __restrict__ C1, int M) {
    __shared__ unsigned short As[128][136];
    __shared__ unsigned short Bs[64][136];
    int tid = threadIdx.x;
    int bm = blockIdx.x * 128;
    int y = blockIdx.y;
    const unsigned short* WT = (y < 2 ? WTl : WTr) + (size_t)(y & 1) * 64 * 128;
    unsigned short* C = (y < 2) ? C0 : C1;
    int bcol = (y & 1) * 64;

    #pragma unroll
    for (int i = 0; i < 8; ++i) {            // A: 128 rows x 16 chunks
        int c = tid + i * 256;
        int row = c >> 4, ko = (c & 15) * 8;
        int gr = bm + row; if (gr >= M) gr = M - 1;
        ushort8 v = *(const ushort8*)(Abf + (size_t)gr * 128 + ko);
        *(ushort8*)(&As[row][ko]) = v;
    }
    #pragma unroll
    for (int i = 0; i < 4; ++i) {            // B^T: 64 rows x 16 chunks
        int c = tid + i * 256;
        int row = c >> 4, ko = (c & 15) * 8;
        ushort8 v = *(const ushort8*)(WT + (size_t)row * 128 + ko);
        *(ushort8*)(&Bs[row][ko]) = v;
    }
    __syncthreads();

    int wid = tid >> 6, lane = tid & 63;
    int wr = (wid >> 1) * 64, wc = (wid & 1) * 32;
    int la = lane & 31, lb = (lane >> 5) * 8;
    f32x16 acc0 = {};
    f32x16 acc1 = {};
    #pragma unroll
    for (int ks = 0; ks < 8; ++ks) {
        int k0 = ks * 16;
        bf16x8 a0 = *(const bf16x8*)(&As[wr + la][k0 + lb]);
        bf16x8 a1 = *(const bf16x8*)(&As[wr + 32 + la][k0 + lb]);
        bf16x8 b  = *(const bf16x8*)(&Bs[wc + la][k0 + lb]);
        acc0 = __builtin_amdgcn_mfma_f32_32x32x16_bf16(a0, b, acc0, 0, 0, 0);
        acc1 = __builtin_amdgcn_mfma_f32_32x32x16_bf16(a1, b, acc1, 0, 0, 0);
    }

    int col = bcol + wc + la;
    int rbase = (lane >> 5) * 4;
    #pragma unroll
    for (int reg = 0; reg < 16; ++reg) {
        int rr = (reg & 3) + 8 * (reg >> 2) + rbase;
        int row0 = bm + wr + rr;
        if (row0 < M) C[(size_t)row0 * 128 + col] = f2bf(acc0[reg]);
        int row1 = bm + wr + 32 + rr;
        if (row1 < M) C[(size_t)row1 * 128 + col] = f2bf(acc1[reg]);
    }
}

// ---------------------------------------------------------------------------
// Fused edge pass (logits + segment-softmax + aggregate). XL/XR bf16 tables.
// Edge loop unrolled 4-deep: 4 row-gathers in flight before any consumption
// (hides ~200-900cy gather latency); online-softmax updates stay in exact
// serial order -> bit-identical to the unrolled=1 version.
// ---------------------------------------------------------------------------

__global__ __launch_bounds__(256) void edge_fused(const unsigned int* __restrict__ XL2,
                                                  const unsigned int* __restrict__ XR2,
                                                  const int* __restrict__ rp,
                                                  const int* __restrict__ csrc,
                                                  const float* __restrict__ att,
                                                  float* __restrict__ hout, int N) {
    int lane = threadIdx.x & 63;
    int node = blockIdx.x * 4 + (threadIdx.x >> 6);
    if (node >= N) return;
    int c0 = lane * 2;                       // 2 channels per lane; head = lane>>4
    float2 a2 = *(const float2*)(att + c0);
    unsigned int xru = XR2[(size_t)node * 64 + lane];
    float xrx = __uint_as_float(xru << 16);
    float xry = __uint_as_float(xru & 0xFFFF0000u);
    int s = rp[node], e = rp[node + 1];
    float m = -INFINITY, den = 0.f, ax = 0.f, ay = 0.f;

#define EF_LOGIT(u, tx, xx, yy)                                       \
    {                                                                 \
        xx = __uint_as_float((u) << 16);                              \
        yy = __uint_as_float((u) & 0xFFFF0000u);                      \
        float v0 = xx + xrx; v0 = (v0 > 0.f) ? v0 : NEG_SLOPE * v0;   \
        float v1 = yy + xry; v1 = (v1 > 0.f) ? v1 : NEG_SLOPE * v1;   \
        tx = fmaf(v0, a2.x, v1 * a2.y);                               \
    }
#define EF_UPDATE(tx, xx, yy)                                         \
    {                                                                 \
        float mnew = fmaxf(m, tx);                                    \
        float sc = __expf(m - mnew);                                  \
        float p = __expf(tx - mnew);                                  \
        den = fmaf(den, sc, p);                                       \
        ax  = fmaf(ax, sc, p * xx);                                   \
        ay  = fmaf(ay, sc, p * yy);                                   \
        m = mnew;                                                     \
    }

    int j = s;
    for (; j + 4 <= e; j += 4) {
        int s0 = csrc[j], s1 = csrc[j + 1], s2 = csrc[j + 2], s3 = csrc[j + 3];
        unsigned int u0 = XL2[(size_t)s0 * 64 + lane];
        unsigned int u1 = XL2[(size_t)s1 * 64 + lane];
        unsigned int u2 = XL2[(size_t)s2 * 64 + lane];
        unsigned int u3 = XL2[(size_t)s3 * 64 + lane];
        float t0, t1, t2, t3, x0, x1, x2, x3, y0, y1, y2, y3;
        EF_LOGIT(u0, t0, x0, y0);
        EF_LOGIT(u1, t1, x1, y1);
        EF_LOGIT(u2, t2, x2, y2);
        EF_LOGIT(u3, t3, x3, y3);
        #pragma unroll
        for (int off = 1; off < 16; off <<= 1) {
            t0 += __shfl_xor(t0, off);
            t1 += __shfl_xor(t1, off);
            t2 += __shfl_xor(t2, off);
            t3 += __shfl_xor(t3, off);
        }
        EF_UPDATE(t0, x0, y0);
        EF_UPDATE(t1, x1, y1);
        EF_UPDATE(t2, x2, y2);
        EF_UPDATE(t3, x3, y3);
    }
    for (; j < e; ++j) {
        int src = csrc[j];
        unsigned int u0 = XL2[(size_t)src * 64 + lane];
        float t0, x0, y0;
        EF_LOGIT(u0, t0, x0, y0);
        #pragma unroll
        for (int off = 1; off < 16; off <<= 1) t0 += __shfl_xor(t0, off);
        EF_UPDATE(t0, x0, y0);
    }
#undef EF_LOGIT
#undef EF_UPDATE

    float inv = 1.f / (den + SM_EPS);
    float2* hp = (float2*)(hout + (size_t)node * 128 + c0);
    float2 o = *hp;
    o.x = fmaf(ax, inv, o.x);
    o.y = fmaf(ay, inv, o.y);
    *hp = o;
}

// h[i][c] = b[0][c] + b[1][c] + b[2][c]
__global__ void init_h(float* __restrict__ h, const float* __restrict__ b3, int total4) {
    int t = blockIdx.x * blockDim.x + threadIdx.x;
    if (t < total4) {
        int c = (t & 31) * 4;
        float4 b0 = *(const float4*)(b3 + c);
        float4 b1 = *(const float4*)(b3 + 128 + c);
        float4 b2 = *(const float4*)(b3 + 256 + c);
        float4 o = {b0.x + b1.x + b2.x, b0.y + b1.y + b2.y,
                    b0.z + b1.z + b2.z, b0.w + b1.w + b2.w};
        *(float4*)(h + (size_t)t * 4) = o;
    }
}

// Final classifier: wave per game (4 nodes -> 512 features), relu, dot fcW.
__global__ __launch_bounds__(256) void final_fc(const float* __restrict__ h2,
                                                const float* __restrict__ fcW,
                                                const float* __restrict__ fcb,
                                                float* __restrict__ out, int G) {
    int lane = threadIdx.x & 63;
    int g = blockIdx.x * 4 + (threadIdx.x >> 6);
    if (g >= G) return;
    const float* hv = h2 + (size_t)g * 512 + lane * 8;
    float4 p0 = *(const float4*)hv;
    float4 p1 = *(const float4*)(hv + 4);
    float v[8] = {p0.x, p0.y, p0.z, p0.w, p1.x, p1.y, p1.z, p1.w};
    float acc0 = 0, acc1 = 0, acc2 = 0, acc3 = 0;
    #pragma unroll
    for (int jj = 0; jj < 8; ++jj) {
        float xv = v[jj] > 0.f ? v[jj] : 0.f;
        float4 w = *(const float4*)(fcW + (size_t)(lane * 8 + jj) * 4);
        acc0 = fmaf(xv, w.x, acc0);
        acc1 = fmaf(xv, w.y, acc1);
        acc2 = fmaf(xv, w.z, acc2);
        acc3 = fmaf(xv, w.w, acc3);
    }
    #pragma unroll
    for (int off = 1; off < 64; off <<= 1) {
        acc0 += __shfl_xor(acc0, off);
        acc1 += __shfl_xor(acc1, off);
        acc2 += __shfl_xor(acc2, off);
        acc3 += __shfl_xor(acc3, off);
    }
    if (lane == 0) {
        float4 o = {acc0 + fcb[0], acc1 + fcb[1], acc2 + fcb[2], acc3 + fcb[3]};
        *(float4*)(out + (size_t)g * 4) = o;
    }
}

// ---------------------------------------------------------------------------

extern "C" void kernel_launch(void* const* d_in, const int* in_sizes, int n_in,
                              void* d_out, int out_size, void* d_ws, size_t ws_size,
                              hipStream_t stream) {
    const float* x    = (const float*)d_in[0];
    const int*   e_f  = (const int*)d_in[1];
    const int*   e_a  = (const int*)d_in[2];
    const int*   e_v  = (const int*)d_in[3];
    const float* W1l  = (const float*)d_in[4];
    const float* W1r  = (const float*)d_in[5];
    const float* att1 = (const float*)d_in[6];
    const float* b1   = (const float*)d_in[7];
    const float* W2l  = (const float*)d_in[8];
    const float* W2r  = (const float*)d_in[9];
    const float* att2 = (const float*)d_in[10];
    const float* b2   = (const float*)d_in[11];
    const float* fcW  = (const float*)d_in[12];
    const float* fcb  = (const float*)d_in[13];
    float* out = (float*)d_out;

    int N = in_sizes[0] / 128;
    int E = in_sizes[1] / 2;

    // workspace carve (~100 MB total)
    char* ws = (char*)d_ws;
    size_t off = 0;
    auto alloc = [&](size_t bytes) -> void* {
        void* p = ws + off;
        off += (bytes + 255) & ~size_t(255);
        return p;
    };
    int*   deg3  = (int*)alloc((size_t)3 * N * 4);
    int*   cur3  = (int*)alloc((size_t)3 * N * 4);
    int*   rp3   = (int*)alloc((size_t)3 * (N + 1) * 4);
    int*   csrc3 = (int*)alloc((size_t)3 * E * 4);
    unsigned short* XLbf = (unsigned short*)alloc((size_t)N * 128 * 2);
    unsigned short* XRbf = (unsigned short*)alloc((size_t)N * 128 * 2);
    float* h1    = (float*)alloc((size_t)N * 128 * 4);
    float* h2    = (float*)alloc((size_t)N * 128 * 4);
    unsigned short* Abf = (unsigned short*)alloc((size_t)N * 128 * 2);
    unsigned short* WT  = (unsigned short*)alloc((size_t)12 * 128 * 128 * 2);

    const int* edges[3] = {e_f, e_a, e_v};

    // ---- CSR build (once; shared by both layers) ----
    hipMemsetAsync(deg3, 0, (size_t)3 * N * 4, stream);
    int ecb = (E + 255) / 256;
    for (int r = 0; r < 3; ++r)
        count_deg<<<ecb, 256, 0, stream>>>(edges[r], deg3 + (size_t)r * N, E);
    scan_deg<<<3, 1024, 0, stream>>>(deg3, rp3, cur3, N);
    for (int r = 0; r < 3; ++r)
        scatter_edges<<<ecb, 256, 0, stream>>>(edges[r], cur3 + (size_t)r * N,
                                               csrc3 + (size_t)r * E, E);

    // ---- weights -> bf16 transposed (once) ----
    transpose_cast_w<<<dim3(16, 3, 4), 256, 0, stream>>>(W1l, W1r, W2l, W2r, WT);

    int nb_rows  = (N + 127) / 128;
    int nb_node4 = (N + 3) / 4;
    int nb_init  = (N * 128 / 4 + 255) / 256;
    int nb_cast  = (N * 128 / 4 + 255) / 256;

    struct Layer {
        const float *in, *att, *b;
        int wtg_l, wtg_r;   // WT group indices (x3 relations each)
        float* hout;
    };
    Layer layers[2] = {
        { x,  att1, b1, 0, 1, h1 },
        { h1, att2, b2, 2, 3, h2 },
    };

    for (int L = 0; L < 2; ++L) {
        Layer& ly = layers[L];
        cast_bf16<<<nb_cast, 256, 0, stream>>>(ly.in, Abf, N * 128 / 4);
        init_h<<<nb_init, 256, 0, stream>>>(ly.hout, ly.b, N * 128 / 4);
        for (int r = 0; r < 3; ++r) {
            const unsigned short* WTl = WT + (size_t)(ly.wtg_l * 3 + r) * 16384;
            const unsigned short* WTr = WT + (size_t)(ly.wtg_r * 3 + r) * 16384;
            gemm_mfma<<<dim3(nb_rows, 4), 256, 0, stream>>>(Abf, WTl, WTr, XLbf, XRbf, N);
            const int* rp   = rp3 + (size_t)r * (N + 1);
            const int* csrc = csrc3 + (size_t)r * E;
            edge_fused<<<nb_node4, 256, 0, stream>>>((const unsigned int*)XLbf,
                                                     (const unsigned int*)XRbf, rp, csrc,
                                                     ly.att + (size_t)r * 128, ly.hout, N);
        }
    }
    int G = N / 4;
    final_fc<<<(G + 3) / 4, 256, 0, stream>>>(h2, fcW, fcb, out, G);
}

// Round 15
// 640.444 us; speedup vs baseline: 2.3852x; 1.0345x over previous
//
#include <hip/hip_runtime.h>
#include <hip/hip_bf16.h>
#include <math.h>

#define NEG_SLOPE 0.2f
#define SM_EPS 1e-16f
#define SCAN_CHUNK 4096

typedef short bf16x8 __attribute__((ext_vector_type(8)));
typedef float f32x16 __attribute__((ext_vector_type(16)));
typedef unsigned short ushort8 __attribute__((ext_vector_type(8)));
typedef unsigned short ushort4v __attribute__((ext_vector_type(4)));

__device__ inline unsigned short f2bf(float f) {
    unsigned int u = __float_as_uint(f);
    unsigned int r = (u + 0x7FFF + ((u >> 16) & 1)) >> 16;  // RNE
    return (unsigned short)r;
}

// ---------------------------------------------------------------------------
// CSR build: fused count (all 3 relations), 3-phase parallel scan, fused
// scatter. All integer-exact.
// ---------------------------------------------------------------------------

__global__ void count_deg3(const int* __restrict__ e0, const int* __restrict__ e1,
                           const int* __restrict__ e2, int* __restrict__ deg3,
                           int E, int N) {
    int r = blockIdx.y;
    const int* edge = (r == 0) ? e0 : (r == 1) ? e1 : e2;
    int t = blockIdx.x * blockDim.x + threadIdx.x;
    if (t < E) atomicAdd(&deg3[(size_t)r * N + edge[E + t]], 1);
}

// Phase A: per-block partial sums over chunks of SCAN_CHUNK.
__global__ __launch_bounds__(256) void scan_partial(const int* __restrict__ deg3,
                                                    int* __restrict__ bsum,
                                                    int N, int nblk) {
    int r = blockIdx.y;
    const int* deg = deg3 + (size_t)r * N;
    int tid = threadIdx.x;
    int tbase = blockIdx.x * SCAN_CHUNK + tid * 16;
    int sum = 0;
    #pragma unroll
    for (int k = 0; k < 16; ++k) {
        int i = tbase + k;
        if (i < N) sum += deg[i];
    }
    #pragma unroll
    for (int off = 1; off < 64; off <<= 1) sum += __shfl_xor(sum, off);
    __shared__ int ws[4];
    int lane = tid & 63, wid = tid >> 6;
    if (lane == 0) ws[wid] = sum;
    __syncthreads();
    if (tid == 0) bsum[(size_t)r * nblk + blockIdx.x] = ws[0] + ws[1] + ws[2] + ws[3];
}

// Phase B: exclusive-scan the (<=256) block sums per relation; write rp[N].
__global__ void scan_mid(int* __restrict__ bsum, int* __restrict__ rp3,
                         int N, int nblk) {
    int r = blockIdx.x;
    int* bs = bsum + (size_t)r * nblk;
    int tid = threadIdx.x;
    int v = (tid < nblk) ? bs[tid] : 0;
    int lane = tid & 63, wid = tid >> 6;
    int incl = v;
    #pragma unroll
    for (int off = 1; off < 64; off <<= 1) {
        int t2 = __shfl_up(incl, off);
        if (lane >= off) incl += t2;
    }
    __shared__ int ws[4];
    if (lane == 63) ws[wid] = incl;
    __syncthreads();
    int woff = 0;
    #pragma unroll
    for (int q = 0; q < 4; ++q) woff += (q < wid) ? ws[q] : 0;
    if (tid < nblk) bs[tid] = woff + incl - v;    // exclusive block offset
    if (tid == 255) rp3[(size_t)r * (N + 1) + N] = woff + incl;  // total
}

// Phase C: per-block exclusive scan of its chunk + block offset; write rp,cur.
__global__ __launch_bounds__(256) void scan_apply(const int* __restrict__ deg3,
                                                  const int* __restrict__ bsum,
                                                  int* __restrict__ rp3,
                                                  int* __restrict__ cur3,
                                                  int N, int nblk) {
    int r = blockIdx.y;
    const int* deg = deg3 + (size_t)r * N;
    int* rp  = rp3 + (size_t)r * (N + 1);
    int* cur = cur3 + (size_t)r * N;
    int boff = bsum[(size_t)r * nblk + blockIdx.x];
    int tid = threadIdx.x;
    int tbase = blockIdx.x * SCAN_CHUNK + tid * 16;
    int vals[16];
    int s = 0;
    #pragma unroll
    for (int k = 0; k < 16; ++k) {
        int i = tbase + k;
        vals[k] = (i < N) ? deg[i] : 0;
        s += vals[k];
    }
    int lane = tid & 63, wid = tid >> 6;
    int incl = s;
    #pragma unroll
    for (int off = 1; off < 64; off <<= 1) {
        int t2 = __shfl_up(incl, off);
        if (lane >= off) incl += t2;
    }
    __shared__ int ws[4];
    if (lane == 63) ws[wid] = incl;
    __syncthreads();
    int woff = 0;
    #pragma unroll
    for (int q = 0; q < 4; ++q) woff += (q < wid) ? ws[q] : 0;
    int run = boff + woff + (incl - s);
    #pragma unroll
    for (int k = 0; k < 16; ++k) {
        int i = tbase + k;
        if (i < N) { rp[i] = run; cur[i] = run; }
        run += vals[k];
    }
}

__global__ void scatter3(const int* __restrict__ e0, const int* __restrict__ e1,
                         const int* __restrict__ e2, int* __restrict__ cur3,
                         int* __restrict__ csrc3, int E, int N) {
    int r = blockIdx.y;
    const int* edge = (r == 0) ? e0 : (r == 1) ? e1 : e2;
    int t = blockIdx.x * blockDim.x + threadIdx.x;
    if (t < E) {
        int src = edge[t];
        int dst = edge[E + t];
        int pos = atomicAdd(&cur3[(size_t)r * N + dst], 1);
        csrc3[(size_t)r * E + pos] = src;
    }
}

// ---------------------------------------------------------------------------
// Precision staging: fp32 -> bf16 casts.
// ---------------------------------------------------------------------------

__global__ void cast_bf16(const float* __restrict__ in, unsigned short* __restrict__ out,
                          int n4) {
    int t = blockIdx.x * blockDim.x + threadIdx.x;
    if (t < n4) {
        float4 v = *(const float4*)(in + (size_t)t * 4);
        ushort4v o = {f2bf(v.x), f2bf(v.y), f2bf(v.z), f2bf(v.w)};
        *(ushort4v*)(out + (size_t)t * 4) = o;
    }
}

__global__ __launch_bounds__(256) void transpose_cast_w(
    const float* __restrict__ W1l, const float* __restrict__ W1r,
    const float* __restrict__ W2l, const float* __restrict__ W2r,
    unsigned short* __restrict__ WT) {
    const float* srcs[4] = {W1l, W1r, W2l, W2r};
    int g = blockIdx.z, r = blockIdx.y;
    const float* W = srcs[g] + (size_t)r * 16384;
    unsigned short* D = WT + (size_t)(g * 3 + r) * 16384;
    int t = blockIdx.x;                    // 16 tiles: 4x4 of 32x32
    int kr = (t >> 2) * 32, cb = (t & 3) * 32;
    __shared__ float tile[32][33];
    int tr = threadIdx.x >> 3, tc4 = (threadIdx.x & 7) * 4;
    float4 v = *(const float4*)(W + (size_t)(kr + tr) * 128 + cb + tc4);
    tile[tr][tc4 + 0] = v.x;
    tile[tr][tc4 + 1] = v.y;
    tile[tr][tc4 + 2] = v.z;
    tile[tr][tc4 + 3] = v.w;
    __syncthreads();
    int c = threadIdx.x >> 3, k4 = (threadIdx.x & 7) * 4;
    ushort4v o = {f2bf(tile[k4 + 0][c]), f2bf(tile[k4 + 1][c]),
                  f2bf(tile[k4 + 2][c]), f2bf(tile[k4 + 3][c])};
    *(ushort4v*)(D + (size_t)(cb + c) * 128 + kr + k4) = o;
}

// ---------------------------------------------------------------------------
// MFMA GEMM: C0 = A @ Wl, C1 = A @ Wr  (M x 128 @ 128 x 128, bf16 in/out).
// Layouts unchanged (m74/m101-verified). LDS rows padded to 136.
// ---------------------------------------------------------------------------

__global__ __launch_bounds__(256) void gemm_mfma(
    const unsigned short* __restrict__ Abf,
    const unsigned short* __restrict__ WTl,
    const unsigned short* __restrict__ WTr,
    unsigned short* __restrict__ C0, unsigned short* __restrict__ C1, int M) {
    __shared__ unsigned short As[128][136];
    __shared__ unsigned short Bs[64][136];
    int tid = threadIdx.x;
    int bm = blockIdx.x * 128;
    int y = blockIdx.y;
    const unsigned short* WT = (y < 2 ? WTl : WTr) + (size_t)(y & 1) * 64 * 128;
    unsigned short* C = (y < 2) ? C0 : C1;
    int bcol = (y & 1) * 64;

    #pragma unroll
    for (int i = 0; i < 8; ++i) {            // A: 128 rows x 16 chunks
        int c = tid + i * 256;
        int row = c >> 4, ko = (c & 15) * 8;
        int gr = bm + row; if (gr >= M) gr = M - 1;
        ushort8 v = *(const ushort8*)(Abf + (size_t)gr * 128 + ko);
        *(ushort8*)(&As[row][ko]) = v;
    }
    #pragma unroll
    for (int i = 0; i < 4; ++i) {            // B^T: 64 rows x 16 chunks
        int c = tid + i * 256;
        int row = c >> 4, ko = (c & 15) * 8;
        ushort8 v = *(const ushort8*)(WT + (size_t)row * 128 + ko);
        *(ushort8*)(&Bs[row][ko]) = v;
    }
    __syncthreads();

    int wid = tid >> 6, lane = tid & 63;
    int wr = (wid >> 1) * 64, wc = (wid & 1) * 32;
    int la = lane & 31, lb = (lane >> 5) * 8;
    f32x16 acc0 = {};
    f32x16 acc1 = {};
    #pragma unroll
    for (int ks = 0; ks < 8; ++ks) {
        int k0 = ks * 16;
        bf16x8 a0 = *(const bf16x8*)(&As[wr + la][k0 + lb]);
        bf16x8 a1 = *(const bf16x8*)(&As[wr + 32 + la][k0 + lb]);
        bf16x8 b  = *(const bf16x8*)(&Bs[wc + la][k0 + lb]);
        acc0 = __builtin_amdgcn_mfma_f32_32x32x16_bf16(a0, b, acc0, 0, 0, 0);
        acc1 = __builtin_amdgcn_mfma_f32_32x32x16_bf16(a1, b, acc1, 0, 0, 0);
    }

    int col = bcol + wc + la;
    int rbase = (lane >> 5) * 4;
    #pragma unroll
    for (int reg = 0; reg < 16; ++reg) {
        int rr = (reg & 3) + 8 * (reg >> 2) + rbase;
        int row0 = bm + wr + rr;
        if (row0 < M) C[(size_t)row0 * 128 + col] = f2bf(acc0[reg]);
        int row1 = bm + wr + 32 + rr;
        if (row1 < M) C[(size_t)row1 * 128 + col] = f2bf(acc1[reg]);
    }
}

// ---------------------------------------------------------------------------
// Fused edge pass (logits + segment-softmax + aggregate). XL/XR bf16 tables.
// Edge loop unrolled 8-deep (then 4, then 1): up to 8 row-gathers in flight;
// online-softmax updates stay in exact CSR order -> bit-identical result.
// ---------------------------------------------------------------------------

__global__ __launch_bounds__(256) void edge_fused(const unsigned int* __restrict__ XL2,
                                                  const unsigned int* __restrict__ XR2,
                                                  const int* __restrict__ rp,
                                                  const int* __restrict__ csrc,
                                                  const float* __restrict__ att,
                                                  float* __restrict__ hout, int N) {
    int lane = threadIdx.x & 63;
    int node = blockIdx.x * 4 + (threadIdx.x >> 6);
    if (node >= N) return;
    int c0 = lane * 2;                       // 2 channels per lane; head = lane>>4
    float2 a2 = *(const float2*)(att + c0);
    unsigned int xru = XR2[(size_t)node * 64 + lane];
    float xrx = __uint_as_float(xru << 16);
    float xry = __uint_as_float(xru & 0xFFFF0000u);
    int s = rp[node], e = rp[node + 1];
    float m = -INFINITY, den = 0.f, ax = 0.f, ay = 0.f;

#define EF_LOGIT(u, tx, xx, yy)                                       \
    {                                                                 \
        xx = __uint_as_float((u) << 16);                              \
        yy = __uint_as_float((u) & 0xFFFF0000u);                      \
        float v0 = xx + xrx; v0 = (v0 > 0.f) ? v0 : NEG_SLOPE * v0;   \
        float v1 = yy + xry; v1 = (v1 > 0.f) ? v1 : NEG_SLOPE * v1;   \
        tx = fmaf(v0, a2.x, v1 * a2.y);                               \
    }
#define EF_UPDATE(tx, xx, yy)                                         \
    {                                                                 \
        float mnew = fmaxf(m, tx);                                    \
        float sc = __expf(m - mnew);                                  \
        float p = __expf(tx - mnew);                                  \
        den = fmaf(den, sc, p);                                       \
        ax  = fmaf(ax, sc, p * xx);                                   \
        ay  = fmaf(ay, sc, p * yy);                                   \
        m = mnew;                                                     \
    }

    int j = s;
    for (; j + 8 <= e; j += 8) {
        int s0 = csrc[j],     s1 = csrc[j + 1], s2 = csrc[j + 2], s3 = csrc[j + 3];
        int s4 = csrc[j + 4], s5 = csrc[j + 5], s6 = csrc[j + 6], s7 = csrc[j + 7];
        unsigned int u0 = XL2[(size_t)s0 * 64 + lane];
        unsigned int u1 = XL2[(size_t)s1 * 64 + lane];
        unsigned int u2 = XL2[(size_t)s2 * 64 + lane];
        unsigned int u3 = XL2[(size_t)s3 * 64 + lane];
        unsigned int u4 = XL2[(size_t)s4 * 64 + lane];
        unsigned int u5 = XL2[(size_t)s5 * 64 + lane];
        unsigned int u6 = XL2[(size_t)s6 * 64 + lane];
        unsigned int u7 = XL2[(size_t)s7 * 64 + lane];
        float t0, t1, t2, t3, t4, t5, t6, t7;
        float x0, x1, x2, x3, x4, x5, x6, x7;
        float y0, y1, y2, y3, y4, y5, y6, y7;
        EF_LOGIT(u0, t0, x0, y0);
        EF_LOGIT(u1, t1, x1, y1);
        EF_LOGIT(u2, t2, x2, y2);
        EF_LOGIT(u3, t3, x3, y3);
        EF_LOGIT(u4, t4, x4, y4);
        EF_LOGIT(u5, t5, x5, y5);
        EF_LOGIT(u6, t6, x6, y6);
        EF_LOGIT(u7, t7, x7, y7);
        #pragma unroll
        for (int off = 1; off < 16; off <<= 1) {
            t0 += __shfl_xor(t0, off);
            t1 += __shfl_xor(t1, off);
            t2 += __shfl_xor(t2, off);
            t3 += __shfl_xor(t3, off);
            t4 += __shfl_xor(t4, off);
            t5 += __shfl_xor(t5, off);
            t6 += __shfl_xor(t6, off);
            t7 += __shfl_xor(t7, off);
        }
        EF_UPDATE(t0, x0, y0);
        EF_UPDATE(t1, x1, y1);
        EF_UPDATE(t2, x2, y2);
        EF_UPDATE(t3, x3, y3);
        EF_UPDATE(t4, x4, y4);
        EF_UPDATE(t5, x5, y5);
        EF_UPDATE(t6, x6, y6);
        EF_UPDATE(t7, x7, y7);
    }
    for (; j + 4 <= e; j += 4) {
        int s0 = csrc[j], s1 = csrc[j + 1], s2 = csrc[j + 2], s3 = csrc[j + 3];
        unsigned int u0 = XL2[(size_t)s0 * 64 + lane];
        unsigned int u1 = XL2[(size_t)s1 * 64 + lane];
        unsigned int u2 = XL2[(size_t)s2 * 64 + lane];
        unsigned int u3 = XL2[(size_t)s3 * 64 + lane];
        float t0, t1, t2, t3, x0, x1, x2, x3, y0, y1, y2, y3;
        EF_LOGIT(u0, t0, x0, y0);
        EF_LOGIT(u1, t1, x1, y1);
        EF_LOGIT(u2, t2, x2, y2);
        EF_LOGIT(u3, t3, x3, y3);
        #pragma unroll
        for (int off = 1; off < 16; off <<= 1) {
            t0 += __shfl_xor(t0, off);
            t1 += __shfl_xor(t1, off);
            t2 += __shfl_xor(t2, off);
            t3 += __shfl_xor(t3, off);
        }
        EF_UPDATE(t0, x0, y0);
        EF_UPDATE(t1, x1, y1);
        EF_UPDATE(t2, x2, y2);
        EF_UPDATE(t3, x3, y3);
    }
    for (; j < e; ++j) {
        int src = csrc[j];
        unsigned int u0 = XL2[(size_t)src * 64 + lane];
        float t0, x0, y0;
        EF_LOGIT(u0, t0, x0, y0);
        #pragma unroll
        for (int off = 1; off < 16; off <<= 1) t0 += __shfl_xor(t0, off);
        EF_UPDATE(t0, x0, y0);
    }
#undef EF_LOGIT
#undef EF_UPDATE

    float inv = 1.f / (den + SM_EPS);
    float2* hp = (float2*)(hout + (size_t)node * 128 + c0);
    float2 o = *hp;
    o.x = fmaf(ax, inv, o.x);
    o.y = fmaf(ay, inv, o.y);
    *hp = o;
}

// h[i][c] = b[0][c] + b[1][c] + b[2][c]
__global__ void init_h(float* __restrict__ h, const float* __restrict__ b3, int total4) {
    int t = blockIdx.x * blockDim.x + threadIdx.x;
    if (t < total4) {
        int c = (t & 31) * 4;
        float4 b0 = *(const float4*)(b3 + c);
        float4 b1 = *(const float4*)(b3 + 128 + c);
        float4 b2 = *(const float4*)(b3 + 256 + c);
        float4 o = {b0.x + b1.x + b2.x, b0.y + b1.y + b2.y,
                    b0.z + b1.z + b2.z, b0.w + b1.w + b2.w};
        *(float4*)(h + (size_t)t * 4) = o;
    }
}

// Final classifier: wave per game (4 nodes -> 512 features), relu, dot fcW.
__global__ __launch_bounds__(256) void final_fc(const float* __restrict__ h2,
                                                const float* __restrict__ fcW,
                                                const float* __restrict__ fcb,
                                                float* __restrict__ out, int G) {
    int lane = threadIdx.x & 63;
    int g = blockIdx.x * 4 + (threadIdx.x >> 6);
    if (g >= G) return;
    const float* hv = h2 + (size_t)g * 512 + lane * 8;
    float4 p0 = *(const float4*)hv;
    float4 p1 = *(const float4*)(hv + 4);
    float v[8] = {p0.x, p0.y, p0.z, p0.w, p1.x, p1.y, p1.z, p1.w};
    float acc0 = 0, acc1 = 0, acc2 = 0, acc3 = 0;
    #pragma unroll
    for (int jj = 0; jj < 8; ++jj) {
        float xv = v[jj] > 0.f ? v[jj] : 0.f;
        float4 w = *(const float4*)(fcW + (size_t)(lane * 8 + jj) * 4);
        acc0 = fmaf(xv, w.x, acc0);
        acc1 = fmaf(xv, w.y, acc1);
        acc2 = fmaf(xv, w.z, acc2);
        acc3 = fmaf(xv, w.w, acc3);
    }
    #pragma unroll
    for (int off = 1; off < 64; off <<= 1) {
        acc0 += __shfl_xor(acc0, off);
        acc1 += __shfl_xor(acc1, off);
        acc2 += __shfl_xor(acc2, off);
        acc3 += __shfl_xor(acc3, off);
    }
    if (lane == 0) {
        float4 o = {acc0 + fcb[0], acc1 + fcb[1], acc2 + fcb[2], acc3 + fcb[3]};
        *(float4*)(out + (size_t)g * 4) = o;
    }
}

// ---------------------------------------------------------------------------

extern "C" void kernel_launch(void* const* d_in, const int* in_sizes, int n_in,
                              void* d_out, int out_size, void* d_ws, size_t ws_size,
                              hipStream_t stream) {
    const float* x    = (const float*)d_in[0];
    const int*   e_f  = (const int*)d_in[1];
    const int*   e_a  = (const int*)d_in[2];
    const int*   e_v  = (const int*)d_in[3];
    const float* W1l  = (const float*)d_in[4];
    const float* W1r  = (const float*)d_in[5];
    const float* att1 = (const float*)d_in[6];
    const float* b1   = (const float*)d_in[7];
    const float* W2l  = (const float*)d_in[8];
    const float* W2r  = (const float*)d_in[9];
    const float* att2 = (const float*)d_in[10];
    const float* b2   = (const float*)d_in[11];
    const float* fcW  = (const float*)d_in[12];
    const float* fcb  = (const float*)d_in[13];
    float* out = (float*)d_out;

    int N = in_sizes[0] / 128;
    int E = in_sizes[1] / 2;
    int nblk = (N + SCAN_CHUNK - 1) / SCAN_CHUNK;

    // workspace carve (~100 MB total)
    char* ws = (char*)d_ws;
    size_t off = 0;
    auto alloc = [&](size_t bytes) -> void* {
        void* p = ws + off;
        off += (bytes + 255) & ~size_t(255);
        return p;
    };
    int*   deg3  = (int*)alloc((size_t)3 * N * 4);
    int*   cur3  = (int*)alloc((size_t)3 * N * 4);
    int*   rp3   = (int*)alloc((size_t)3 * (N + 1) * 4);
    int*   csrc3 = (int*)alloc((size_t)3 * E * 4);
    int*   bsum  = (int*)alloc((size_t)3 * 256 * 4);
    unsigned short* XLbf = (unsigned short*)alloc((size_t)N * 128 * 2);
    unsigned short* XRbf = (unsigned short*)alloc((size_t)N * 128 * 2);
    float* h1    = (float*)alloc((size_t)N * 128 * 4);
    float* h2    = (float*)alloc((size_t)N * 128 * 4);
    unsigned short* Abf = (unsigned short*)alloc((size_t)N * 128 * 2);
    unsigned short* WT  = (unsigned short*)alloc((size_t)12 * 128 * 128 * 2);

    // ---- CSR build (once; shared by both layers) ----
    hipMemsetAsync(deg3, 0, (size_t)3 * N * 4, stream);
    int ecb = (E + 255) / 256;
    count_deg3<<<dim3(ecb, 3), 256, 0, stream>>>(e_f, e_a, e_v, deg3, E, N);
    scan_partial<<<dim3(nblk, 3), 256, 0, stream>>>(deg3, bsum, N, nblk);
    scan_mid<<<3, 256, 0, stream>>>(bsum, rp3, N, nblk);
    scan_apply<<<dim3(nblk, 3), 256, 0, stream>>>(deg3, bsum, rp3, cur3, N, nblk);
    scatter3<<<dim3(ecb, 3), 256, 0, stream>>>(e_f, e_a, e_v, cur3, csrc3, E, N);

    // ---- weights -> bf16 transposed (once) ----
    transpose_cast_w<<<dim3(16, 3, 4), 256, 0, stream>>>(W1l, W1r, W2l, W2r, WT);

    int nb_rows  = (N + 127) / 128;
    int nb_node4 = (N + 3) / 4;
    int nb_init  = (N * 128 / 4 + 255) / 256;
    int nb_cast  = (N * 128 / 4 + 255) / 256;

    struct Layer {
        const float *in, *att, *b;
        int wtg_l, wtg_r;   // WT group indices (x3 relations each)
        float* hout;
    };
    Layer layers[2] = {
        { x,  att1, b1, 0, 1, h1 },
        { h1, att2, b2, 2, 3, h2 },
    };

    for (int L = 0; L < 2; ++L) {
        Layer& ly = layers[L];
        cast_bf16<<<nb_cast, 256, 0, stream>>>(ly.in, Abf, N * 128 / 4);
        init_h<<<nb_init, 256, 0, stream>>>(ly.hout, ly.b, N * 128 / 4);
        for (int r = 0; r < 3; ++r) {
            const unsigned short* WTl = WT + (size_t)(ly.wtg_l * 3 + r) * 16384;
            const unsigned short* WTr = WT + (size_t)(ly.wtg_r * 3 + r) * 16384;
            gemm_mfma<<<dim3(nb_rows, 4), 256, 0, stream>>>(Abf, WTl, WTr, XLbf, XRbf, N);
            const int* rp   = rp3 + (size_t)r * (N + 1);
            const int* csrc = csrc3 + (size_t)r * E;
            edge_fused<<<nb_node4, 256, 0, stream>>>((const unsigned int*)XLbf,
                                                     (const unsigned int*)XRbf, rp, csrc,
                                                     ly.att + (size_t)r * 128, ly.hout, N);
        }
    }
    int G = N / 4;
    final_fc<<<(G + 3) / 4, 256, 0, stream>>>(h2, fcW, fcb, out, G);
}

// Round 16
// 611.733 us; speedup vs baseline: 2.4971x; 1.0469x over previous
//
#include <hip/hip_runtime.h>
#include <hip/hip_bf16.h>
#include <math.h>

#define NEG_SLOPE 0.2f
#define SM_EPS 1e-16f
#define SCAN_CHUNK 4096
#define BIN_SHIFT 10          // 1024 dst nodes per bin; <=64 bins for N<=65536

typedef short bf16x8 __attribute__((ext_vector_type(8)));
typedef float f32x16 __attribute__((ext_vector_type(16)));
typedef unsigned short ushort8 __attribute__((ext_vector_type(8)));
typedef unsigned short ushort4v __attribute__((ext_vector_type(4)));

__device__ inline unsigned short f2bf(float f) {
    unsigned int u = __float_as_uint(f);
    unsigned int r = (u + 0x7FFF + ((u >> 16) & 1)) >> 16;  // RNE
    return (unsigned short)r;
}

// ---------------------------------------------------------------------------
// CSR build: count (3 relations fused), 3-phase parallel scan, then a
// two-phase binned scatter that avoids cross-XCD partial-line write
// amplification (round-15 scatter3: 88MB HBM writes for a 6MB output).
// ---------------------------------------------------------------------------

__global__ void count_deg3(const int* __restrict__ e0, const int* __restrict__ e1,
                           const int* __restrict__ e2, int* __restrict__ deg3,
                           int E, int N) {
    int r = blockIdx.y;
    const int* edge = (r == 0) ? e0 : (r == 1) ? e1 : e2;
    int t = blockIdx.x * blockDim.x + threadIdx.x;
    if (t < E) atomicAdd(&deg3[(size_t)r * N + edge[E + t]], 1);
}

// Phase A: per-block partial sums over chunks of SCAN_CHUNK.
__global__ __launch_bounds__(256) void scan_partial(const int* __restrict__ deg3,
                                                    int* __restrict__ bsum,
                                                    int N, int nblk) {
    int r = blockIdx.y;
    const int* deg = deg3 + (size_t)r * N;
    int tid = threadIdx.x;
    int tbase = blockIdx.x * SCAN_CHUNK + tid * 16;
    int sum = 0;
    #pragma unroll
    for (int k = 0; k < 16; ++k) {
        int i = tbase + k;
        if (i < N) sum += deg[i];
    }
    #pragma unroll
    for (int off = 1; off < 64; off <<= 1) sum += __shfl_xor(sum, off);
    __shared__ int ws[4];
    int lane = tid & 63, wid = tid >> 6;
    if (lane == 0) ws[wid] = sum;
    __syncthreads();
    if (tid == 0) bsum[(size_t)r * nblk + blockIdx.x] = ws[0] + ws[1] + ws[2] + ws[3];
}

// Phase B: exclusive-scan the (<=256) block sums per relation; write rp[N].
__global__ void scan_mid(int* __restrict__ bsum, int* __restrict__ rp3,
                         int N, int nblk) {
    int r = blockIdx.x;
    int* bs = bsum + (size_t)r * nblk;
    int tid = threadIdx.x;
    int v = (tid < nblk) ? bs[tid] : 0;
    int lane = tid & 63, wid = tid >> 6;
    int incl = v;
    #pragma unroll
    for (int off = 1; off < 64; off <<= 1) {
        int t2 = __shfl_up(incl, off);
        if (lane >= off) incl += t2;
    }
    __shared__ int ws[4];
    if (lane == 63) ws[wid] = incl;
    __syncthreads();
    int woff = 0;
    #pragma unroll
    for (int q = 0; q < 4; ++q) woff += (q < wid) ? ws[q] : 0;
    if (tid < nblk) bs[tid] = woff + incl - v;    // exclusive block offset
    if (tid == 255) rp3[(size_t)r * (N + 1) + N] = woff + incl;  // total
}

// Phase C: per-block exclusive scan of its chunk + block offset; write rp,cur.
__global__ __launch_bounds__(256) void scan_apply(const int* __restrict__ deg3,
                                                  const int* __restrict__ bsum,
                                                  int* __restrict__ rp3,
                                                  int* __restrict__ cur3,
                                                  int N, int nblk) {
    int r = blockIdx.y;
    const int* deg = deg3 + (size_t)r * N;
    int* rp  = rp3 + (size_t)r * (N + 1);
    int* cur = cur3 + (size_t)r * N;
    int boff = bsum[(size_t)r * nblk + blockIdx.x];
    int tid = threadIdx.x;
    int tbase = blockIdx.x * SCAN_CHUNK + tid * 16;
    int vals[16];
    int s = 0;
    #pragma unroll
    for (int k = 0; k < 16; ++k) {
        int i = tbase + k;
        vals[k] = (i < N) ? deg[i] : 0;
        s += vals[k];
    }
    int lane = tid & 63, wid = tid >> 6;
    int incl = s;
    #pragma unroll
    for (int off = 1; off < 64; off <<= 1) {
        int t2 = __shfl_up(incl, off);
        if (lane >= off) incl += t2;
    }
    __shared__ int ws[4];
    if (lane == 63) ws[wid] = incl;
    __syncthreads();
    int woff = 0;
    #pragma unroll
    for (int q = 0; q < 4; ++q) woff += (q < wid) ? ws[q] : 0;
    int run = boff + woff + (incl - s);
    #pragma unroll
    for (int k = 0; k < 16; ++k) {
        int i = tbase + k;
        if (i < N) { rp[i] = run; cur[i] = run; }
        run += vals[k];
    }
}

// gcur[r][b] = rp[b*1024]: per-bin write cursors into the CSR index space.
__global__ void init_gcur(const int* __restrict__ rp3, int* __restrict__ gcur, int N) {
    int r = blockIdx.x, b = threadIdx.x;   // 64 threads
    int idx = b << BIN_SHIFT;
    if (idx > N) idx = N;
    gcur[r * 64 + b] = rp3[(size_t)r * (N + 1) + idx];
}

// Phase 1 of scatter: stage 4096 edges in LDS, group by dst-bin, flush each
// bin as a coalesced run into ebin at the bin's global cursor.
__global__ __launch_bounds__(256) void bin_edges(const int* __restrict__ e0,
                                                 const int* __restrict__ e1,
                                                 const int* __restrict__ e2,
                                                 int* __restrict__ gcur,
                                                 uint2* __restrict__ ebin,
                                                 int E, int N) {
    int r = blockIdx.y;
    const int* edge = (r == 0) ? e0 : (r == 1) ? e1 : e2;
    __shared__ uint2 stage[4096];
    __shared__ unsigned char sbin[4096];
    __shared__ int cnt[64], curb[64], offc[64], gbase[64];
    int tid = threadIdx.x;
    if (tid < 64) cnt[tid] = 0;
    __syncthreads();
    int base = blockIdx.x * 4096;
    int mysrc[16], mydst[16];
    #pragma unroll
    for (int k = 0; k < 16; ++k) {
        int i = base + k * 256 + tid;
        int sv = -1, dv = 0;
        if (i < E) {
            sv = edge[i];
            dv = edge[E + i];
            atomicAdd(&cnt[dv >> BIN_SHIFT], 1);
        }
        mysrc[k] = sv; mydst[k] = dv;
    }
    __syncthreads();
    if (tid < 64) {
        int c = cnt[tid];
        int incl = c;
        #pragma unroll
        for (int off = 1; off < 64; off <<= 1) {
            int t2 = __shfl_up(incl, off);
            if (tid >= off) incl += t2;
        }
        int excl = incl - c;
        offc[tid] = excl;
        curb[tid] = excl;
        gbase[tid] = (c > 0) ? atomicAdd(&gcur[r * 64 + tid], c) : 0;
    }
    __syncthreads();
    #pragma unroll
    for (int k = 0; k < 16; ++k) {
        if (mysrc[k] >= 0) {
            int b = mydst[k] >> BIN_SHIFT;
            int p = atomicAdd(&curb[b], 1);
            stage[p] = make_uint2((unsigned)mysrc[k], (unsigned)mydst[k]);
            sbin[p] = (unsigned char)b;
        }
    }
    __syncthreads();
    int total = offc[63] + cnt[63];
    for (int s = tid; s < total; s += 256) {
        int b = sbin[s];
        ebin[(size_t)r * E + gbase[b] + (s - offc[b])] = stage[s];
    }
}

// Phase 2: per-bin local scatter. cur3/csrc ranges per bin are ~4KB/~40KB ->
// L2-hot, lines written once.
__global__ __launch_bounds__(256) void scatter_local(const uint2* __restrict__ ebin,
                                                     const int* __restrict__ rp3,
                                                     int* __restrict__ cur3,
                                                     int* __restrict__ csrc3,
                                                     int E, int N) {
    int r = blockIdx.z, b = blockIdx.y, z = blockIdx.x;
    int nb1 = b << BIN_SHIFT;
    if (nb1 >= N) return;
    int nb2 = (b + 1) << BIN_SHIFT;
    if (nb2 > N) nb2 = N;
    const int* rp = rp3 + (size_t)r * (N + 1);
    int s0 = rp[nb1], s1 = rp[nb2];
    int len = s1 - s0;
    int per = (len + (int)gridDim.x - 1) / (int)gridDim.x;
    int a0 = s0 + z * per;
    int a1 = a0 + per; if (a1 > s1) a1 = s1;
    for (int i = a0 + threadIdx.x; i < a1; i += 256) {
        uint2 ed = ebin[(size_t)r * E + i];
        int pos = atomicAdd(&cur3[(size_t)r * N + (int)ed.y], 1);
        csrc3[(size_t)r * E + pos] = (int)ed.x;
    }
}

// ---------------------------------------------------------------------------
// Precision staging: fp32 -> bf16 casts.
// ---------------------------------------------------------------------------

__global__ void cast_bf16(const float* __restrict__ in, unsigned short* __restrict__ out,
                          int n4) {
    int t = blockIdx.x * blockDim.x + threadIdx.x;
    if (t < n4) {
        float4 v = *(const float4*)(in + (size_t)t * 4);
        ushort4v o = {f2bf(v.x), f2bf(v.y), f2bf(v.z), f2bf(v.w)};
        *(ushort4v*)(out + (size_t)t * 4) = o;
    }
}

__global__ __launch_bounds__(256) void transpose_cast_w(
    const float* __restrict__ W1l, const float* __restrict__ W1r,
    const float* __restrict__ W2l, const float* __restrict__ W2r,
    unsigned short* __restrict__ WT) {
    const float* srcs[4] = {W1l, W1r, W2l, W2r};
    int g = blockIdx.z, r = blockIdx.y;
    const float* W = srcs[g] + (size_t)r * 16384;
    unsigned short* D = WT + (size_t)(g * 3 + r) * 16384;
    int t = blockIdx.x;                    // 16 tiles: 4x4 of 32x32
    int kr = (t >> 2) * 32, cb = (t & 3) * 32;
    __shared__ float tile[32][33];
    int tr = threadIdx.x >> 3, tc4 = (threadIdx.x & 7) * 4;
    float4 v = *(const float4*)(W + (size_t)(kr + tr) * 128 + cb + tc4);
    tile[tr][tc4 + 0] = v.x;
    tile[tr][tc4 + 1] = v.y;
    tile[tr][tc4 + 2] = v.z;
    tile[tr][tc4 + 3] = v.w;
    __syncthreads();
    int c = threadIdx.x >> 3, k4 = (threadIdx.x & 7) * 4;
    ushort4v o = {f2bf(tile[k4 + 0][c]), f2bf(tile[k4 + 1][c]),
                  f2bf(tile[k4 + 2][c]), f2bf(tile[k4 + 3][c])};
    *(ushort4v*)(D + (size_t)(cb + c) * 128 + kr + k4) = o;
}

// ---------------------------------------------------------------------------
// MFMA GEMM: C0 = A @ Wl, C1 = A @ Wr  (M x 128 @ 128 x 128, bf16 in/out).
// Layouts unchanged (m74/m101-verified). LDS rows padded to 136.
// ---------------------------------------------------------------------------

__global__ __launch_bounds__(256) void gemm_mfma(
    const unsigned short* __restrict__ Abf,
    const unsigned short* __restrict__ WTl,
    const unsigned short* __restrict__ WTr,
    unsigned short* __restrict__ C0, unsigned short* __restrict__ C1, int M) {
    __shared__ unsigned short As[128][136];
    __shared__ unsigned short Bs[64][136];
    int tid = threadIdx.x;
    int bm = blockIdx.x * 128;
    int y = blockIdx.y;
    const unsigned short* WT = (y < 2 ? WTl : WTr) + (size_t)(y & 1) * 64 * 128;
    unsigned short* C = (y < 2) ? C0 : C1;
    int bcol = (y & 1) * 64;

    #pragma unroll
    for (int i = 0; i < 8; ++i) {            // A: 128 rows x 16 chunks
        int c = tid + i * 256;
        int row = c >> 4, ko = (c & 15) * 8;
        int gr = bm + row; if (gr >= M) gr = M - 1;
        ushort8 v = *(const ushort8*)(Abf + (size_t)gr * 128 + ko);
        *(ushort8*)(&As[row][ko]) = v;
    }
    #pragma unroll
    for (int i = 0; i < 4; ++i) {            // B^T: 64 rows x 16 chunks
        int c = tid + i * 256;
        int row = c >> 4, ko = (c & 15) * 8;
        ushort8 v = *(const ushort8*)(WT + (size_t)row * 128 + ko);
        *(ushort8*)(&Bs[row][ko]) = v;
    }
    __syncthreads();

    int wid = tid >> 6, lane = tid & 63;
    int wr = (wid >> 1) * 64, wc = (wid & 1) * 32;
    int la = lane & 31, lb = (lane >> 5) * 8;
    f32x16 acc0 = {};
    f32x16 acc1 = {};
    #pragma unroll
    for (int ks = 0; ks < 8; ++ks) {
        int k0 = ks * 16;
        bf16x8 a0 = *(const bf16x8*)(&As[wr + la][k0 + lb]);
        bf16x8 a1 = *(const bf16x8*)(&As[wr + 32 + la][k0 + lb]);
        bf16x8 b  = *(const bf16x8*)(&Bs[wc + la][k0 + lb]);
        acc0 = __builtin_amdgcn_mfma_f32_32x32x16_bf16(a0, b, acc0, 0, 0, 0);
        acc1 = __builtin_amdgcn_mfma_f32_32x32x16_bf16(a1, b, acc1, 0, 0, 0);
    }

    int col = bcol + wc + la;
    int rbase = (lane >> 5) * 4;
    #pragma unroll
    for (int reg = 0; reg < 16; ++reg) {
        int rr = (reg & 3) + 8 * (reg >> 2) + rbase;
        int row0 = bm + wr + rr;
        if (row0 < M) C[(size_t)row0 * 128 + col] = f2bf(acc0[reg]);
        int row1 = bm + wr + 32 + rr;
        if (row1 < M) C[(size_t)row1 * 128 + col] = f2bf(acc1[reg]);
    }
}

// ---------------------------------------------------------------------------
// Fused edge pass (logits + segment-softmax + aggregate). XL/XR bf16 tables.
// Edge loop unrolled 8/4/1-deep; online-softmax updates in exact CSR order.
// ---------------------------------------------------------------------------

__global__ __launch_bounds__(256) void edge_fused(const unsigned int* __restrict__ XL2,
                                                  const unsigned int* __restrict__ XR2,
                                                  const int* __restrict__ rp,
                                                  const int* __restrict__ csrc,
                                                  const float* __restrict__ att,
                                                  float* __restrict__ hout, int N) {
    int lane = threadIdx.x & 63;
    int node = blockIdx.x * 4 + (threadIdx.x >> 6);
    if (node >= N) return;
    int c0 = lane * 2;                       // 2 channels per lane; head = lane>>4
    float2 a2 = *(const float2*)(att + c0);
    unsigned int xru = XR2[(size_t)node * 64 + lane];
    float xrx = __uint_as_float(xru << 16);
    float xry = __uint_as_float(xru & 0xFFFF0000u);
    int s = rp[node], e = rp[node + 1];
    float m = -INFINITY, den = 0.f, ax = 0.f, ay = 0.f;

#define EF_LOGIT(u, tx, xx, yy)                                       \
    {                                                                 \
        xx = __uint_as_float((u) << 16);                              \
        yy = __uint_as_float((u) & 0xFFFF0000u);                      \
        float v0 = xx + xrx; v0 = (v0 > 0.f) ? v0 : NEG_SLOPE * v0;   \
        float v1 = yy + xry; v1 = (v1 > 0.f) ? v1 : NEG_SLOPE * v1;   \
        tx = fmaf(v0, a2.x, v1 * a2.y);                               \
    }
#define EF_UPDATE(tx, xx, yy)                                         \
    {                                                                 \
        float mnew = fmaxf(m, tx);                                    \
        float sc = __expf(m - mnew);                                  \
        float p = __expf(tx - mnew);                                  \
        den = fmaf(den, sc, p);                                       \
        ax  = fmaf(ax, sc, p * xx);                                   \
        ay  = fmaf(ay, sc, p * yy);                                   \
        m = mnew;                                                     \
    }

    int j = s;
    for (; j + 8 <= e; j += 8) {
        int s0 = csrc[j],     s1 = csrc[j + 1], s2 = csrc[j + 2], s3 = csrc[j + 3];
        int s4 = csrc[j + 4], s5 = csrc[j + 5], s6 = csrc[j + 6], s7 = csrc[j + 7];
        unsigned int u0 = XL2[(size_t)s0 * 64 + lane];
        unsigned int u1 = XL2[(size_t)s1 * 64 + lane];
        unsigned int u2 = XL2[(size_t)s2 * 64 + lane];
        unsigned int u3 = XL2[(size_t)s3 * 64 + lane];
        unsigned int u4 = XL2[(size_t)s4 * 64 + lane];
        unsigned int u5 = XL2[(size_t)s5 * 64 + lane];
        unsigned int u6 = XL2[(size_t)s6 * 64 + lane];
        unsigned int u7 = XL2[(size_t)s7 * 64 + lane];
        float t0, t1, t2, t3, t4, t5, t6, t7;
        float x0, x1, x2, x3, x4, x5, x6, x7;
        float y0, y1, y2, y3, y4, y5, y6, y7;
        EF_LOGIT(u0, t0, x0, y0);
        EF_LOGIT(u1, t1, x1, y1);
        EF_LOGIT(u2, t2, x2, y2);
        EF_LOGIT(u3, t3, x3, y3);
        EF_LOGIT(u4, t4, x4, y4);
        EF_LOGIT(u5, t5, x5, y5);
        EF_LOGIT(u6, t6, x6, y6);
        EF_LOGIT(u7, t7, x7, y7);
        #pragma unroll
        for (int off = 1; off < 16; off <<= 1) {
            t0 += __shfl_xor(t0, off);
            t1 += __shfl_xor(t1, off);
            t2 += __shfl_xor(t2, off);
            t3 += __shfl_xor(t3, off);
            t4 += __shfl_xor(t4, off);
            t5 += __shfl_xor(t5, off);
            t6 += __shfl_xor(t6, off);
            t7 += __shfl_xor(t7, off);
        }
        EF_UPDATE(t0, x0, y0);
        EF_UPDATE(t1, x1, y1);
        EF_UPDATE(t2, x2, y2);
        EF_UPDATE(t3, x3, y3);
        EF_UPDATE(t4, x4, y4);
        EF_UPDATE(t5, x5, y5);
        EF_UPDATE(t6, x6, y6);
        EF_UPDATE(t7, x7, y7);
    }
    for (; j + 4 <= e; j += 4) {
        int s0 = csrc[j], s1 = csrc[j + 1], s2 = csrc[j + 2], s3 = csrc[j + 3];
        unsigned int u0 = XL2[(size_t)s0 * 64 + lane];
        unsigned int u1 = XL2[(size_t)s1 * 64 + lane];
        unsigned int u2 = XL2[(size_t)s2 * 64 + lane];
        unsigned int u3 = XL2[(size_t)s3 * 64 + lane];
        float t0, t1, t2, t3, x0, x1, x2, x3, y0, y1, y2, y3;
        EF_LOGIT(u0, t0, x0, y0);
        EF_LOGIT(u1, t1, x1, y1);
        EF_LOGIT(u2, t2, x2, y2);
        EF_LOGIT(u3, t3, x3, y3);
        #pragma unroll
        for (int off = 1; off < 16; off <<= 1) {
            t0 += __shfl_xor(t0, off);
            t1 += __shfl_xor(t1, off);
            t2 += __shfl_xor(t2, off);
            t3 += __shfl_xor(t3, off);
        }
        EF_UPDATE(t0, x0, y0);
        EF_UPDATE(t1, x1, y1);
        EF_UPDATE(t2, x2, y2);
        EF_UPDATE(t3, x3, y3);
    }
    for (; j < e; ++j) {
        int src = csrc[j];
        unsigned int u0 = XL2[(size_t)src * 64 + lane];
        float t0, x0, y0;
        EF_LOGIT(u0, t0, x0, y0);
        #pragma unroll
        for (int off = 1; off < 16; off <<= 1) t0 += __shfl_xor(t0, off);
        EF_UPDATE(t0, x0, y0);
    }
#undef EF_LOGIT
#undef EF_UPDATE

    float inv = 1.f / (den + SM_EPS);
    float2* hp = (float2*)(hout + (size_t)node * 128 + c0);
    float2 o = *hp;
    o.x = fmaf(ax, inv, o.x);
    o.y = fmaf(ay, inv, o.y);
    *hp = o;
}

// h[i][c] = b[0][c] + b[1][c] + b[2][c]
__global__ void init_h(float* __restrict__ h, const float* __restrict__ b3, int total4) {
    int t = blockIdx.x * blockDim.x + threadIdx.x;
    if (t < total4) {
        int c = (t & 31) * 4;
        float4 b0 = *(const float4*)(b3 + c);
        float4 b1 = *(const float4*)(b3 + 128 + c);
        float4 b2 = *(const float4*)(b3 + 256 + c);
        float4 o = {b0.x + b1.x + b2.x, b0.y + b1.y + b2.y,
                    b0.z + b1.z + b2.z, b0.w + b1.w + b2.w};
        *(float4*)(h + (size_t)t * 4) = o;
    }
}

// Final classifier: wave per game (4 nodes -> 512 features), relu, dot fcW.
__global__ __launch_bounds__(256) void final_fc(const float* __restrict__ h2,
                                                const float* __restrict__ fcW,
                                                const float* __restrict__ fcb,
                                                float* __restrict__ out, int G) {
    int lane = threadIdx.x & 63;
    int g = blockIdx.x * 4 + (threadIdx.x >> 6);
    if (g >= G) return;
    const float* hv = h2 + (size_t)g * 512 + lane * 8;
    float4 p0 = *(const float4*)hv;
    float4 p1 = *(const float4*)(hv + 4);
    float v[8] = {p0.x, p0.y, p0.z, p0.w, p1.x, p1.y, p1.z, p1.w};
    float acc0 = 0, acc1 = 0, acc2 = 0, acc3 = 0;
    #pragma unroll
    for (int jj = 0; jj < 8; ++jj) {
        float xv = v[jj] > 0.f ? v[jj] : 0.f;
        float4 w = *(const float4*)(fcW + (size_t)(lane * 8 + jj) * 4);
        acc0 = fmaf(xv, w.x, acc0);
        acc1 = fmaf(xv, w.y, acc1);
        acc2 = fmaf(xv, w.z, acc2);
        acc3 = fmaf(xv, w.w, acc3);
    }
    #pragma unroll
    for (int off = 1; off < 64; off <<= 1) {
        acc0 += __shfl_xor(acc0, off);
        acc1 += __shfl_xor(acc1, off);
        acc2 += __shfl_xor(acc2, off);
        acc3 += __shfl_xor(acc3, off);
    }
    if (lane == 0) {
        float4 o = {acc0 + fcb[0], acc1 + fcb[1], acc2 + fcb[2], acc3 + fcb[3]};
        *(float4*)(out + (size_t)g * 4) = o;
    }
}

// ---------------------------------------------------------------------------

extern "C" void kernel_launch(void* const* d_in, const int* in_sizes, int n_in,
                              void* d_out, int out_size, void* d_ws, size_t ws_size,
                              hipStream_t stream) {
    const float* x    = (const float*)d_in[0];
    const int*   e_f  = (const int*)d_in[1];
    const int*   e_a  = (const int*)d_in[2];
    const int*   e_v  = (const int*)d_in[3];
    const float* W1l  = (const float*)d_in[4];
    const float* W1r  = (const float*)d_in[5];
    const float* att1 = (const float*)d_in[6];
    const float* b1   = (const float*)d_in[7];
    const float* W2l  = (const float*)d_in[8];
    const float* W2r  = (const float*)d_in[9];
    const float* att2 = (const float*)d_in[10];
    const float* b2   = (const float*)d_in[11];
    const float* fcW  = (const float*)d_in[12];
    const float* fcb  = (const float*)d_in[13];
    float* out = (float*)d_out;

    int N = in_sizes[0] / 128;
    int E = in_sizes[1] / 2;
    int nblk = (N + SCAN_CHUNK - 1) / SCAN_CHUNK;

    // workspace carve (~112 MB total)
    char* ws = (char*)d_ws;
    size_t off = 0;
    auto alloc = [&](size_t bytes) -> void* {
        void* p = ws + off;
        off += (bytes + 255) & ~size_t(255);
        return p;
    };
    int*   deg3  = (int*)alloc((size_t)3 * N * 4);
    int*   cur3  = (int*)alloc((size_t)3 * N * 4);
    int*   rp3   = (int*)alloc((size_t)3 * (N + 1) * 4);
    int*   csrc3 = (int*)alloc((size_t)3 * E * 4);
    int*   bsum  = (int*)alloc((size_t)3 * 256 * 4);
    int*   gcur  = (int*)alloc((size_t)3 * 64 * 4);
    uint2* ebin  = (uint2*)alloc((size_t)3 * E * 8);
    unsigned short* XLbf = (unsigned short*)alloc((size_t)N * 128 * 2);
    unsigned short* XRbf = (unsigned short*)alloc((size_t)N * 128 * 2);
    float* h1    = (float*)alloc((size_t)N * 128 * 4);
    float* h2    = (float*)alloc((size_t)N * 128 * 4);
    unsigned short* Abf = (unsigned short*)alloc((size_t)N * 128 * 2);
    unsigned short* WT  = (unsigned short*)alloc((size_t)12 * 128 * 128 * 2);

    // ---- CSR build (once; shared by both layers) ----
    hipMemsetAsync(deg3, 0, (size_t)3 * N * 4, stream);
    int ecb = (E + 255) / 256;
    int ebb = (E + 4095) / 4096;
    count_deg3<<<dim3(ecb, 3), 256, 0, stream>>>(e_f, e_a, e_v, deg3, E, N);
    scan_partial<<<dim3(nblk, 3), 256, 0, stream>>>(deg3, bsum, N, nblk);
    scan_mid<<<3, 256, 0, stream>>>(bsum, rp3, N, nblk);
    scan_apply<<<dim3(nblk, 3), 256, 0, stream>>>(deg3, bsum, rp3, cur3, N, nblk);
    init_gcur<<<3, 64, 0, stream>>>(rp3, gcur, N);
    bin_edges<<<dim3(ebb, 3), 256, 0, stream>>>(e_f, e_a, e_v, gcur, ebin, E, N);
    scatter_local<<<dim3(8, 64, 3), 256, 0, stream>>>(ebin, rp3, cur3, csrc3, E, N);

    // ---- weights -> bf16 transposed (once) ----
    transpose_cast_w<<<dim3(16, 3, 4), 256, 0, stream>>>(W1l, W1r, W2l, W2r, WT);

    int nb_rows  = (N + 127) / 128;
    int nb_node4 = (N + 3) / 4;
    int nb_init  = (N * 128 / 4 + 255) / 256;
    int nb_cast  = (N * 128 / 4 + 255) / 256;

    struct Layer {
        const float *in, *att, *b;
        int wtg_l, wtg_r;   // WT group indices (x3 relations each)
        float* hout;
    };
    Layer layers[2] = {
        { x,  att1, b1, 0, 1, h1 },
        { h1, att2, b2, 2, 3, h2 },
    };

    for (int L = 0; L < 2; ++L) {
        Layer& ly = layers[L];
        cast_bf16<<<nb_cast, 256, 0, stream>>>(ly.in, Abf, N * 128 / 4);
        init_h<<<nb_init, 256, 0, stream>>>(ly.hout, ly.b, N * 128 / 4);
        for (int r = 0; r < 3; ++r) {
            const unsigned short* WTl = WT + (size_t)(ly.wtg_l * 3 + r) * 16384;
            const unsigned short* WTr = WT + (size_t)(ly.wtg_r * 3 + r) * 16384;
            gemm_mfma<<<dim3(nb_rows, 4), 256, 0, stream>>>(Abf, WTl, WTr, XLbf, XRbf, N);
            const int* rp   = rp3 + (size_t)r * (N + 1);
            const int* csrc = csrc3 + (size_t)r * E;
            edge_fused<<<nb_node4, 256, 0, stream>>>((const unsigned int*)XLbf,
                                                     (const unsigned int*)XRbf, rp, csrc,
                                                     ly.att + (size_t)r * 128, ly.hout, N);
        }
    }
    int G = N / 4;
    final_fc<<<(G + 3) / 4, 256, 0, stream>>>(h2, fcW, fcb, out, G);
}